// Round 12
// baseline (1356.632 us; speedup 1.0000x reference)
//
#include <hip/hip_runtime.h>
#include <hip/hip_bf16.h>

#define BB   16
#define SS   512
#define DD   768
#define NHH  4
#define HDD  192
#define DFFD 2048
#define NID  18
#define NW   510          // S - W + 1
#define NWIN (BB * NW)    // 8160 windows
#define MR   (NWIN * 3)   // 24480 encoder rows

typedef __attribute__((ext_vector_type(8))) short bf16x8;
typedef __attribute__((ext_vector_type(4))) short bf16x4;
typedef __attribute__((ext_vector_type(4))) float f32x4;
typedef __hip_bfloat16 bf16;

__device__ __forceinline__ float b2f(bf16 x) { return __bfloat162float(x); }
__device__ __forceinline__ float s2f(short s) {
    return __bfloat162float(__builtin_bit_cast(bf16, (unsigned short)s));
}
__device__ __forceinline__ short f2s(float f) {
    return (short)__builtin_bit_cast(unsigned short, __float2bfloat16(f));
}

// ---------------- fused f32 -> bf16 conversion for all 5 tensors ----------------
__device__ __forceinline__ void cvt_range(const float4* __restrict__ in,
                                          ushort4* __restrict__ out, int i)
{
    float4 f = in[i];
    ushort4 u;
    u.x = __builtin_bit_cast(unsigned short, __float2bfloat16(f.x));
    u.y = __builtin_bit_cast(unsigned short, __float2bfloat16(f.y));
    u.z = __builtin_bit_cast(unsigned short, __float2bfloat16(f.z));
    u.w = __builtin_bit_cast(unsigned short, __float2bfloat16(f.w));
    out[i] = u;
}

#define CN0 1572864   // hidden
#define CN1 442368    // in_proj_w
#define CN2 147456    // out_proj_w
#define CN3 393216    // ffn_w1
#define CN4 393216    // ffn_w2
#define CT  (CN0 + CN1 + CN2 + CN3 + CN4)

__global__ __launch_bounds__(256) void cvt_all_kernel(
    const float4* __restrict__ s0, ushort4* __restrict__ d0,
    const float4* __restrict__ s1, ushort4* __restrict__ d1,
    const float4* __restrict__ s2, ushort4* __restrict__ d2,
    const float4* __restrict__ s3, ushort4* __restrict__ d3,
    const float4* __restrict__ s4, ushort4* __restrict__ d4)
{
    for (int i = blockIdx.x * 256 + threadIdx.x; i < CT; i += gridDim.x * 256) {
        int j = i;
        if (j < CN0) { cvt_range(s0, d0, j); continue; }
        j -= CN0;
        if (j < CN1) { cvt_range(s1, d1, j); continue; }
        j -= CN1;
        if (j < CN2) { cvt_range(s2, d2, j); continue; }
        j -= CN2;
        if (j < CN3) { cvt_range(s3, d3, j); continue; }
        j -= CN3;
        cvt_range(s4, d4, j);
    }
}

// ---------------- 128x128 bf16 NT GEMM, BK=64, swizzled LDS, prefetch-under-MFMA ----
// C[M,N] = A[M,K] * Bm[N,K]^T + bias (+optional ReLU). 1-D grid + bijective
// XCD swizzle. LDS [128 rows][128 B] per operand; 16B chunk c of row r stored
// at phys slot c^(r&7) via pre-swizzled GLOBAL source; ds_read applies the
// same XOR (rule #21). K-loop: {ds_read -> lgkm0 -> barrier -> prefetch t+1
// into SAME buffer -> MFMA (covers load flight) -> vmcnt0 -> barrier}.
template<bool RELU>
__global__ void gemm_bt(const bf16* __restrict__ A, const bf16* __restrict__ Bm,
                        const float* __restrict__ bias, bf16* __restrict__ C,
                        int M, int N, int K, int nx)
{
    __shared__ __align__(16) char smem[32768];
    char* smemc = smem;

    const int nwg  = gridDim.x;
    const int orig = blockIdx.x;
    const int xcd  = orig & 7;
    const int idx  = orig >> 3;
    const int q8   = nwg >> 3, r8 = nwg & 7;
    const int newid = (xcd < r8 ? xcd * (q8 + 1) : r8 * (q8 + 1) + (xcd - r8) * q8) + idx;
    const int row0 = (newid / nx) * 128;
    const int col0 = (newid % nx) * 128;

    const int tid = threadIdx.x;
    const int ln  = tid & 63;
    const int wv  = tid >> 6;
    const int wm = (wv >> 1) * 64;
    const int wn = (wv & 1) * 64;
    const int lrow  = ln & 15;
    const int kslot = ln >> 4;
    const int xk0 = (kslot * 16)      ^ ((lrow & 7) << 4);
    const int xk1 = (64 + kslot * 16) ^ ((lrow & 7) << 4);

    // staging: wave wv, issue i covers chunks wv*256 + i*64 + ln
    // chunk -> row = wv*32 + i*8 + (ln>>3), phys slot = ln&7
    const int srow = ln >> 3;                     // 0..7 (== r&7 for all i)
    const int ce   = ((ln & 7) ^ srow) * 8;       // pre-swizzled source elem
    const int rb8  = wv * 32 + srow;
    const bf16* pA[4];
    const bf16* pB[4];
    #pragma unroll
    for (int i = 0; i < 4; ++i) {
        int ar = row0 + rb8 + i * 8;
        if (ar > M - 1) ar = M - 1;
        pA[i] = A  + (size_t)ar * K + ce;
        pB[i] = Bm + (size_t)(col0 + rb8 + i * 8) * K + ce;
    }

    f32x4 acc[4][4] = {};

    // prologue: stage K-tile 0
    #pragma unroll
    for (int i = 0; i < 4; ++i) {
        __builtin_amdgcn_global_load_lds(
            (const __attribute__((address_space(1))) void*)(pA[i]),
            (__attribute__((address_space(3))) void*)(smemc + wv * 4096 + i * 1024), 16, 0, 0);
        __builtin_amdgcn_global_load_lds(
            (const __attribute__((address_space(1))) void*)(pB[i]),
            (__attribute__((address_space(3))) void*)(smemc + 16384 + wv * 4096 + i * 1024), 16, 0, 0);
    }
    asm volatile("s_waitcnt vmcnt(0)" ::: "memory");
    __builtin_amdgcn_sched_barrier(0);
    __builtin_amdgcn_s_barrier();

    for (int k0 = 0; k0 < K; k0 += 64) {
        // ds_read current tile into registers
        bf16x8 a0[4], a1[4], b0[4], b1[4];
        #pragma unroll
        for (int mi = 0; mi < 4; ++mi) {
            const int rb = (wm + mi * 16 + lrow) * 128;
            a0[mi] = *(const bf16x8*)(smemc + rb + xk0);
            a1[mi] = *(const bf16x8*)(smemc + rb + xk1);
        }
        #pragma unroll
        for (int ni = 0; ni < 4; ++ni) {
            const int rb = 16384 + (wn + ni * 16 + lrow) * 128;
            b0[ni] = *(const bf16x8*)(smemc + rb + xk0);
            b1[ni] = *(const bf16x8*)(smemc + rb + xk1);
        }
        asm volatile("s_waitcnt lgkmcnt(0)" ::: "memory");
        __builtin_amdgcn_sched_barrier(0);
        __builtin_amdgcn_s_barrier();          // all waves done reading buffer
        __builtin_amdgcn_sched_barrier(0);

        // prefetch next K-tile into the SAME buffer (safe: all reads done)
        const int k1 = k0 + 64;
        if (k1 < K) {
            #pragma unroll
            for (int i = 0; i < 4; ++i) {
                __builtin_amdgcn_global_load_lds(
                    (const __attribute__((address_space(1))) void*)(pA[i] + k1),
                    (__attribute__((address_space(3))) void*)(smemc + wv * 4096 + i * 1024), 16, 0, 0);
                __builtin_amdgcn_global_load_lds(
                    (const __attribute__((address_space(1))) void*)(pB[i] + k1),
                    (__attribute__((address_space(3))) void*)(smemc + 16384 + wv * 4096 + i * 1024), 16, 0, 0);
            }
        }

        // MFMA burst — covers the prefetch flight
        #pragma unroll
        for (int mi = 0; mi < 4; ++mi)
            #pragma unroll
            for (int ni = 0; ni < 4; ++ni) {
                acc[mi][ni] = __builtin_amdgcn_mfma_f32_16x16x32_bf16(a0[mi], b0[ni], acc[mi][ni], 0, 0, 0);
                acc[mi][ni] = __builtin_amdgcn_mfma_f32_16x16x32_bf16(a1[mi], b1[ni], acc[mi][ni], 0, 0, 0);
            }

        asm volatile("s_waitcnt vmcnt(0)" ::: "memory");
        __builtin_amdgcn_sched_barrier(0);
        __builtin_amdgcn_s_barrier();          // prefetched tile visible to all
        __builtin_amdgcn_sched_barrier(0);
    }

    #pragma unroll
    for (int mi = 0; mi < 4; ++mi) {
        #pragma unroll
        for (int ni = 0; ni < 4; ++ni) {
            const int col = col0 + wn + ni * 16 + lrow;
            const float bb = bias[col];
            #pragma unroll
            for (int r = 0; r < 4; ++r) {
                const int row = row0 + wm + mi * 16 + (ln >> 4) * 4 + r;
                if (row < M) {
                    float v = acc[mi][ni][r] + bb;
                    if (RELU) v = fmaxf(v, 0.0f);
                    C[(size_t)row * N + col] = __float2bfloat16(v);
                }
            }
        }
    }
}

// ---------------- attention over W=3 per (window, head): one wave each ----------------
__global__ __launch_bounds__(256) void attn_kernel(const bf16* __restrict__ qkv, bf16* __restrict__ o)
{
    const int m  = blockIdx.x;
    const int h  = threadIdx.x >> 6;
    const int ln = threadIdx.x & 63;
    const int bb = m / NW, n = m - bb * NW;
    const bool act = ln < 48;
    const size_t base = (size_t)(bb * SS + n) * (3 * DD) + h * HDD + 4 * ln;
    float q[3][4], k[3][4], v[3][4];
    #pragma unroll
    for (int j = 0; j < 3; ++j) {
        if (act) {
            const size_t idx = base + (size_t)j * (3 * DD);
            ushort4 q4 = *(const ushort4*)(qkv + idx);
            ushort4 k4 = *(const ushort4*)(qkv + idx + DD);
            ushort4 v4 = *(const ushort4*)(qkv + idx + 2 * DD);
            q[j][0] = s2f((short)q4.x); q[j][1] = s2f((short)q4.y);
            q[j][2] = s2f((short)q4.z); q[j][3] = s2f((short)q4.w);
            k[j][0] = s2f((short)k4.x); k[j][1] = s2f((short)k4.y);
            k[j][2] = s2f((short)k4.z); k[j][3] = s2f((short)k4.w);
            v[j][0] = s2f((short)v4.x); v[j][1] = s2f((short)v4.y);
            v[j][2] = s2f((short)v4.z); v[j][3] = s2f((short)v4.w);
        } else {
            #pragma unroll
            for (int c = 0; c < 4; ++c) { q[j][c] = 0.f; k[j][c] = 0.f; v[j][c] = 0.f; }
        }
    }
    float s[3][3];
    #pragma unroll
    for (int i = 0; i < 3; ++i)
        #pragma unroll
        for (int j = 0; j < 3; ++j)
            s[i][j] = q[i][0]*k[j][0] + q[i][1]*k[j][1] + q[i][2]*k[j][2] + q[i][3]*k[j][3];
    #pragma unroll
    for (int off = 32; off >= 1; off >>= 1)
        #pragma unroll
        for (int i = 0; i < 3; ++i)
            #pragma unroll
            for (int j = 0; j < 3; ++j)
                s[i][j] += __shfl_xor(s[i][j], off);
    const float scale = 0.07216878364870322f; // 1/sqrt(192)
    float p[3][3];
    #pragma unroll
    for (int i = 0; i < 3; ++i) {
        float mx = fmaxf(s[i][0], fmaxf(s[i][1], s[i][2])) * scale;
        float e0 = expf(s[i][0] * scale - mx);
        float e1 = expf(s[i][1] * scale - mx);
        float e2 = expf(s[i][2] * scale - mx);
        float inv = 1.0f / (e0 + e1 + e2);
        p[i][0] = e0 * inv; p[i][1] = e1 * inv; p[i][2] = e2 * inv;
    }
    if (act) {
        #pragma unroll
        for (int i = 0; i < 3; ++i) {
            bf16x4 o4;
            #pragma unroll
            for (int c = 0; c < 4; ++c)
                o4[c] = f2s(p[i][0]*v[0][c] + p[i][1]*v[1][c] + p[i][2]*v[2][c]);
            *(bf16x4*)(o + (size_t)(m * 3 + i) * DD + h * HDD + 4 * ln) = o4;
        }
    }
}

// ---------------- residual + LayerNorm (LN1): one WAVE per row, 4 rows/block ----------------
__global__ __launch_bounds__(256) void ln1_kernel(const bf16* __restrict__ xa,
                                                  const bf16* __restrict__ xb,
                                                  const float* __restrict__ gamma,
                                                  const float* __restrict__ beta,
                                                  bf16* __restrict__ out)
{
    const int r  = blockIdx.x * 4 + (threadIdx.x >> 6);
    const int ln = threadIdx.x & 63;
    const size_t rb = (size_t)r * DD;
    const int m = r / 3, i = r - m * 3;
    const int bb = m / NW, n = m - bb * NW;
    const size_t ab = (size_t)(bb * SS + n + i) * DD;
    const int e0 = ln * 8, e1 = 512 + ln * 4;
    bf16x8 a0 = *(const bf16x8*)(xa + ab + e0);
    bf16x8 b0 = *(const bf16x8*)(xb + rb + e0);
    bf16x4 a1 = *(const bf16x4*)(xa + ab + e1);
    bf16x4 b1 = *(const bf16x4*)(xb + rb + e1);
    float v[12];
    #pragma unroll
    for (int c = 0; c < 8; ++c) v[c] = s2f(a0[c]) + s2f(b0[c]);
    #pragma unroll
    for (int c = 0; c < 4; ++c) v[8 + c] = s2f(a1[c]) + s2f(b1[c]);
    float s1 = 0.f, s2 = 0.f;
    #pragma unroll
    for (int c = 0; c < 12; ++c) { s1 += v[c]; s2 += v[c] * v[c]; }
    #pragma unroll
    for (int off = 32; off >= 1; off >>= 1) {
        s1 += __shfl_xor(s1, off);
        s2 += __shfl_xor(s2, off);
    }
    const float mean = s1 * (1.0f / 768.0f);
    const float var  = fmaxf(s2 * (1.0f / 768.0f) - mean * mean, 0.0f);
    const float inv  = rsqrtf(var + 1e-5f);
    float4 g0 = *(const float4*)(gamma + e0);
    float4 g1 = *(const float4*)(gamma + e0 + 4);
    float4 g2 = *(const float4*)(gamma + e1);
    float4 t0 = *(const float4*)(beta + e0);
    float4 t1 = *(const float4*)(beta + e0 + 4);
    float4 t2 = *(const float4*)(beta + e1);
    const float gg[12] = {g0.x,g0.y,g0.z,g0.w,g1.x,g1.y,g1.z,g1.w,g2.x,g2.y,g2.z,g2.w};
    const float tt[12] = {t0.x,t0.y,t0.z,t0.w,t1.x,t1.y,t1.z,t1.w,t2.x,t2.y,t2.z,t2.w};
    bf16x8 o0; bf16x4 o1;
    #pragma unroll
    for (int c = 0; c < 8; ++c) o0[c] = f2s((v[c] - mean) * inv * gg[c] + tt[c]);
    #pragma unroll
    for (int c = 0; c < 4; ++c) o1[c] = f2s((v[8 + c] - mean) * inv * gg[8 + c] + tt[8 + c]);
    *(bf16x8*)(out + rb + e0) = o0;
    *(bf16x4*)(out + rb + e1) = o1;
}

// ---------------- fused residual + LN2 + max-pool + align + intent + window_num ----------------
__global__ __launch_bounds__(256) void ln2_pool_intent_kernel(
    const bf16* __restrict__ x, const bf16* __restrict__ f,
    const float* __restrict__ gamma, const float* __restrict__ beta,
    const float* __restrict__ iw, const float* __restrict__ ib,
    const int* __restrict__ seq,
    float* __restrict__ pred, float* __restrict__ align, float* __restrict__ wn_out)
{
    const int m  = blockIdx.x;
    const int bb = m / NW, n = m - bb * NW;
    const int wv = threadIdx.x >> 6, ln = threadIdx.x & 63;
    __shared__ float vsh[3][DD];
    __shared__ float pl[DD];
    if (wv < 3) {
        const size_t rb = (size_t)(m * 3 + wv) * DD;
        const int e0 = ln * 8, e1 = 512 + ln * 4;
        bf16x8 a0 = *(const bf16x8*)(x + rb + e0);
        bf16x8 b0 = *(const bf16x8*)(f + rb + e0);
        bf16x4 a1 = *(const bf16x4*)(x + rb + e1);
        bf16x4 b1 = *(const bf16x4*)(f + rb + e1);
        float v[12];
        #pragma unroll
        for (int c = 0; c < 8; ++c) v[c] = s2f(a0[c]) + s2f(b0[c]);
        #pragma unroll
        for (int c = 0; c < 4; ++c) v[8 + c] = s2f(a1[c]) + s2f(b1[c]);
        float s1 = 0.f, s2 = 0.f;
        #pragma unroll
        for (int c = 0; c < 12; ++c) { s1 += v[c]; s2 += v[c] * v[c]; }
        #pragma unroll
        for (int off = 32; off >= 1; off >>= 1) {
            s1 += __shfl_xor(s1, off);
            s2 += __shfl_xor(s2, off);
        }
        const float mean = s1 * (1.0f / 768.0f);
        const float var  = fmaxf(s2 * (1.0f / 768.0f) - mean * mean, 0.0f);
        const float inv  = rsqrtf(var + 1e-5f);
        float4 g0 = *(const float4*)(gamma + e0);
        float4 g1 = *(const float4*)(gamma + e0 + 4);
        float4 g2 = *(const float4*)(gamma + e1);
        float4 t0 = *(const float4*)(beta + e0);
        float4 t1 = *(const float4*)(beta + e0 + 4);
        float4 t2 = *(const float4*)(beta + e1);
        const float gg[12] = {g0.x,g0.y,g0.z,g0.w,g1.x,g1.y,g1.z,g1.w,g2.x,g2.y,g2.z,g2.w};
        const float tt[12] = {t0.x,t0.y,t0.z,t0.w,t1.x,t1.y,t1.z,t1.w,t2.x,t2.y,t2.z,t2.w};
        #pragma unroll
        for (int c = 0; c < 8; ++c) vsh[wv][e0 + c] = (v[c] - mean) * inv * gg[c] + tt[c];
        #pragma unroll
        for (int c = 0; c < 4; ++c) vsh[wv][e1 + c] = (v[8 + c] - mean) * inv * gg[8 + c] + tt[8 + c];
    }
    __syncthreads();
    const size_t ab = (size_t)bb * 512 * DD;
    #pragma unroll
    for (int t = 0; t < 3; ++t) {
        const int d = threadIdx.x + t * 256;
        float mx = fmaxf(vsh[0][d], fmaxf(vsh[1][d], vsh[2][d]));
        pl[d] = mx;
        align[ab + (size_t)(n + 1) * DD + d] = mx;
        if (n == 0)      align[ab + d] = mx;
        if (n == NW - 1) align[ab + (size_t)511 * DD + d] = mx;
    }
    if (m == 0 && threadIdx.x < BB) {
        int wn = seq[threadIdx.x] - 2;
        if (wn < 1) wn = 1;
        wn_out[threadIdx.x] = (float)wn;
    }
    __syncthreads();
    for (int c = wv; c < NID; c += 4) {
        float sum = 0.0f;
        #pragma unroll
        for (int t = 0; t < 12; ++t) {
            const int d = ln + t * 64;
            sum += pl[d] * iw[(size_t)c * DD + d];
        }
        #pragma unroll
        for (int off = 32; off >= 1; off >>= 1)
            sum += __shfl_xor(sum, off);
        if (ln == 0) pred[(size_t)m * NID + c] = sum + ib[c];
    }
}

extern "C" void kernel_launch(void* const* d_in, const int* in_sizes, int n_in,
                              void* d_out, int out_size, void* d_ws, size_t ws_size,
                              hipStream_t stream)
{
    const float* hidden   = (const float*)d_in[0];
    const int*   seq_lens = (const int*)d_in[1];
    const float* in_w     = (const float*)d_in[2];
    const float* in_b     = (const float*)d_in[3];
    const float* out_w    = (const float*)d_in[4];
    const float* out_b    = (const float*)d_in[5];
    const float* ln1_g    = (const float*)d_in[6];
    const float* ln1_bb   = (const float*)d_in[7];
    const float* ln2_g    = (const float*)d_in[8];
    const float* ln2_bb   = (const float*)d_in[9];
    const float* f1_w     = (const float*)d_in[10];
    const float* f1_b     = (const float*)d_in[11];
    const float* f2_w     = (const float*)d_in[12];
    const float* f2_b     = (const float*)d_in[13];
    const float* it_w     = (const float*)d_in[14];
    const float* it_b     = (const float*)d_in[15];

    // ---- compact workspace layout (liveness-based reuse) ----
    char* ws = (char*)d_ws;
    bf16*  hid_bf   = (bf16*)(ws + 0);          // 12,582,912 B
    bf16*  win_bf   = (bf16*)(ws + 12582912);   //  3,538,944
    bf16*  wout_bf  = (bf16*)(ws + 16121856);   //  1,179,648
    bf16*  wf1_bf   = (bf16*)(ws + 17301504);   //  3,145,728
    bf16*  wf2_bf   = (bf16*)(ws + 20447232);   //  3,145,728
    bf16*  qkv_bf   = (bf16*)(ws + 23592960);   // R1: qkv -> oproj -> f
    bf16*  oproj_bf = qkv_bf;
    bf16*  f_bf     = qkv_bf;
    bf16*  o_bf     = (bf16*)(ws + 61341696);   // R2: o
    bf16*  x_bf     = (bf16*)(ws + 98942976);   // R3
    const size_t H_BASE = 136544256ull;
    bf16*  h_bf     = (bf16*)(ws + H_BASE);     // FFN hidden (chunked vs ws_size)

    float* out_pred  = (float*)d_out;           // 146880
    float* out_wn    = out_pred + 146880;       // 16
    float* out_align = out_pred + 146896;       // 6,291,456

    // single fused f32 -> bf16 pass for all 5 tensors
    cvt_all_kernel<<<2048, 256, 0, stream>>>(
        (const float4*)hidden, (ushort4*)hid_bf,
        (const float4*)in_w,   (ushort4*)win_bf,
        (const float4*)out_w,  (ushort4*)wout_bf,
        (const float4*)f1_w,   (ushort4*)wf1_bf,
        (const float4*)f2_w,   (ushort4*)wf2_bf);

    // QKV (per-position, shared across windows): [8192,768] x [2304,768]^T  (BK=64 128²)
    gemm_bt<false><<<18 * 64, 256, 0, stream>>>(hid_bf, win_bf, in_b, qkv_bf,
                                                8192, 2304, 768, 18);
    // attention per (window, head)
    attn_kernel<<<NWIN, 256, 0, stream>>>(qkv_bf, o_bf);
    // out_proj: [24480,768] x [768,768]^T  (BK=64 128²; writes R1, qkv dead)
    gemm_bt<false><<<6 * 192, 256, 0, stream>>>(o_bf, wout_bf, out_b, oproj_bf,
                                                MR, 768, 768, 6);
    // x = LN1(win + oproj)  (wave-per-row)
    ln1_kernel<<<MR / 4, 256, 0, stream>>>(hid_bf, oproj_bf, ln1_g, ln1_bb, x_bf);

    // FFN, chunked over rows so the 2048-wide hidden fits in remaining workspace.
    size_t avail = ws_size > H_BASE ? ws_size - H_BASE : 0;
    long cap = (long)(avail / (DFFD * 2));
    cap = (cap / 128) * 128;
    if (cap < 128) cap = 128;
    if (cap > MR) cap = MR;
    for (int r0 = 0; r0 < MR; r0 += (int)cap) {
        int mc = MR - r0; if (mc > cap) mc = (int)cap;
        int mt128 = (mc + 127) / 128;
        // FFN1: rows x [2048,768]^T + ReLU  (BK=64 128²)
        gemm_bt<true><<<mt128 * 16, 256, 0, stream>>>(x_bf + (size_t)r0 * DD, wf1_bf, f1_b, h_bf,
                                                      mc, DFFD, 768, 16);
        // FFN2: rows x [768,2048]^T  (BK=64 128²; writes f into R1, oproj dead)
        gemm_bt<false><<<mt128 * 6, 256, 0, stream>>>(h_bf, wf2_bf, f2_b,
                                                      f_bf + (size_t)r0 * DD,
                                                      mc, 768, DFFD, 6);
    }

    // fused residual + LN2 + max-pool + align + intent + window_num
    ln2_pool_intent_kernel<<<NWIN, 256, 0, stream>>>(x_bf, f_bf, ln2_g, ln2_bb, it_w, it_b,
                                                     seq_lens, out_pred, out_align, out_wn);
}

// Round 13
// 377.749 us; speedup vs baseline: 3.5914x; 3.5914x over previous
//
#include <hip/hip_runtime.h>
#include <hip/hip_bf16.h>

#define BB   16
#define SS   512
#define DD   768
#define NHH  4
#define HDD  192
#define DFFD 2048
#define NID  18
#define NW   510          // S - W + 1
#define NWIN (BB * NW)    // 8160 windows
#define MR   (NWIN * 3)   // 24480 encoder rows

typedef __attribute__((ext_vector_type(8))) short bf16x8;
typedef __attribute__((ext_vector_type(4))) short bf16x4;
typedef __attribute__((ext_vector_type(4))) float f32x4;
typedef __hip_bfloat16 bf16;

__device__ __forceinline__ float b2f(bf16 x) { return __bfloat162float(x); }
__device__ __forceinline__ float s2f(short s) {
    return __bfloat162float(__builtin_bit_cast(bf16, (unsigned short)s));
}
__device__ __forceinline__ short f2s(float f) {
    return (short)__builtin_bit_cast(unsigned short, __float2bfloat16(f));
}

// ---------------- fused f32 -> bf16 conversion for all 5 tensors ----------------
__device__ __forceinline__ void cvt_range(const float4* __restrict__ in,
                                          ushort4* __restrict__ out, int i)
{
    float4 f = in[i];
    ushort4 u;
    u.x = __builtin_bit_cast(unsigned short, __float2bfloat16(f.x));
    u.y = __builtin_bit_cast(unsigned short, __float2bfloat16(f.y));
    u.z = __builtin_bit_cast(unsigned short, __float2bfloat16(f.z));
    u.w = __builtin_bit_cast(unsigned short, __float2bfloat16(f.w));
    out[i] = u;
}

#define CN0 1572864   // hidden
#define CN1 442368    // in_proj_w
#define CN2 147456    // out_proj_w
#define CN3 393216    // ffn_w1
#define CN4 393216    // ffn_w2
#define CT  (CN0 + CN1 + CN2 + CN3 + CN4)

__global__ __launch_bounds__(256) void cvt_all_kernel(
    const float4* __restrict__ s0, ushort4* __restrict__ d0,
    const float4* __restrict__ s1, ushort4* __restrict__ d1,
    const float4* __restrict__ s2, ushort4* __restrict__ d2,
    const float4* __restrict__ s3, ushort4* __restrict__ d3,
    const float4* __restrict__ s4, ushort4* __restrict__ d4)
{
    for (int i = blockIdx.x * 256 + threadIdx.x; i < CT; i += gridDim.x * 256) {
        int j = i;
        if (j < CN0) { cvt_range(s0, d0, j); continue; }
        j -= CN0;
        if (j < CN1) { cvt_range(s1, d1, j); continue; }
        j -= CN1;
        if (j < CN2) { cvt_range(s2, d2, j); continue; }
        j -= CN2;
        if (j < CN3) { cvt_range(s3, d3, j); continue; }
        j -= CN3;
        cvt_range(s4, d4, j);
    }
}

// ---------------- 128x128 bf16 NT GEMM, BK=64, swizzled LDS ----------------
// C[M,N] = A[M,K] * Bm[N,K]^T + bias (+optional ReLU). 1-D grid + bijective
// XCD swizzle. LDS [128 rows][128 B] per operand; 16B chunk c of row r stored
// at phys slot c^(r&7) via pre-swizzled GLOBAL source; ds_read applies the
// same XOR (rule #21). BK=64 halves the per-K drain count vs BK=32.
// VERIFIED round 11: total 377.6 µs; top gemm 95.5 µs, conflicts 0.
// NOTE (round 12 post-mortem): do NOT insert sched_barrier fences / same-buffer
// prefetch here — it forces all 16 fragments live at once -> scratch spills
// (WRITE_SIZE 38 MB -> 990 MB, 3.6x total regression).
template<bool RELU>
__global__ void gemm_bt(const bf16* __restrict__ A, const bf16* __restrict__ Bm,
                        const float* __restrict__ bias, bf16* __restrict__ C,
                        int M, int N, int K, int nx)
{
    __shared__ __align__(16) char smem[32768];
    char* smemc = smem;

    const int nwg  = gridDim.x;
    const int orig = blockIdx.x;
    const int xcd  = orig & 7;
    const int idx  = orig >> 3;
    const int q8   = nwg >> 3, r8 = nwg & 7;
    const int newid = (xcd < r8 ? xcd * (q8 + 1) : r8 * (q8 + 1) + (xcd - r8) * q8) + idx;
    const int row0 = (newid / nx) * 128;
    const int col0 = (newid % nx) * 128;

    const int tid = threadIdx.x;
    const int ln  = tid & 63;
    const int wv  = tid >> 6;
    const int wm = (wv >> 1) * 64;
    const int wn = (wv & 1) * 64;
    const int lrow  = ln & 15;
    const int kslot = ln >> 4;
    const int xk0 = (kslot * 16)      ^ ((lrow & 7) << 4);
    const int xk1 = (64 + kslot * 16) ^ ((lrow & 7) << 4);

    // staging: wave wv, issue i covers chunks wv*256 + i*64 + ln
    // chunk -> row = wv*32 + i*8 + (ln>>3), phys slot = ln&7
    const int srow = ln >> 3;                     // 0..7 (== r&7 for all i)
    const int ce   = ((ln & 7) ^ srow) * 8;       // pre-swizzled source elem
    const int rb8  = wv * 32 + srow;
    const bf16* pA[4];
    const bf16* pB[4];
    #pragma unroll
    for (int i = 0; i < 4; ++i) {
        int ar = row0 + rb8 + i * 8;
        if (ar > M - 1) ar = M - 1;
        pA[i] = A  + (size_t)ar * K + ce;
        pB[i] = Bm + (size_t)(col0 + rb8 + i * 8) * K + ce;
    }

    f32x4 acc[4][4] = {};

    for (int k0 = 0; k0 < K; k0 += 64) {
        #pragma unroll
        for (int i = 0; i < 4; ++i) {
            __builtin_amdgcn_global_load_lds(
                (const __attribute__((address_space(1))) void*)(pA[i] + k0),
                (__attribute__((address_space(3))) void*)(smemc + wv * 4096 + i * 1024), 16, 0, 0);
            __builtin_amdgcn_global_load_lds(
                (const __attribute__((address_space(1))) void*)(pB[i] + k0),
                (__attribute__((address_space(3))) void*)(smemc + 16384 + wv * 4096 + i * 1024), 16, 0, 0);
        }
        __syncthreads();
        bf16x8 a0[4], a1[4], b0[4], b1[4];
        #pragma unroll
        for (int mi = 0; mi < 4; ++mi) {
            const int rb = (wm + mi * 16 + lrow) * 128;
            a0[mi] = *(const bf16x8*)(smemc + rb + xk0);
            a1[mi] = *(const bf16x8*)(smemc + rb + xk1);
        }
        #pragma unroll
        for (int ni = 0; ni < 4; ++ni) {
            const int rb = 16384 + (wn + ni * 16 + lrow) * 128;
            b0[ni] = *(const bf16x8*)(smemc + rb + xk0);
            b1[ni] = *(const bf16x8*)(smemc + rb + xk1);
        }
        #pragma unroll
        for (int mi = 0; mi < 4; ++mi)
            #pragma unroll
            for (int ni = 0; ni < 4; ++ni) {
                acc[mi][ni] = __builtin_amdgcn_mfma_f32_16x16x32_bf16(a0[mi], b0[ni], acc[mi][ni], 0, 0, 0);
                acc[mi][ni] = __builtin_amdgcn_mfma_f32_16x16x32_bf16(a1[mi], b1[ni], acc[mi][ni], 0, 0, 0);
            }
        __syncthreads();
    }

    #pragma unroll
    for (int mi = 0; mi < 4; ++mi) {
        #pragma unroll
        for (int ni = 0; ni < 4; ++ni) {
            const int col = col0 + wn + ni * 16 + lrow;
            const float bb = bias[col];
            #pragma unroll
            for (int r = 0; r < 4; ++r) {
                const int row = row0 + wm + mi * 16 + (ln >> 4) * 4 + r;
                if (row < M) {
                    float v = acc[mi][ni][r] + bb;
                    if (RELU) v = fmaxf(v, 0.0f);
                    C[(size_t)row * N + col] = __float2bfloat16(v);
                }
            }
        }
    }
}

// ---------------- attention over W=3 per (window, head): one wave each ----------------
__global__ __launch_bounds__(256) void attn_kernel(const bf16* __restrict__ qkv, bf16* __restrict__ o)
{
    const int m  = blockIdx.x;
    const int h  = threadIdx.x >> 6;
    const int ln = threadIdx.x & 63;
    const int bb = m / NW, n = m - bb * NW;
    const bool act = ln < 48;
    const size_t base = (size_t)(bb * SS + n) * (3 * DD) + h * HDD + 4 * ln;
    float q[3][4], k[3][4], v[3][4];
    #pragma unroll
    for (int j = 0; j < 3; ++j) {
        if (act) {
            const size_t idx = base + (size_t)j * (3 * DD);
            ushort4 q4 = *(const ushort4*)(qkv + idx);
            ushort4 k4 = *(const ushort4*)(qkv + idx + DD);
            ushort4 v4 = *(const ushort4*)(qkv + idx + 2 * DD);
            q[j][0] = s2f((short)q4.x); q[j][1] = s2f((short)q4.y);
            q[j][2] = s2f((short)q4.z); q[j][3] = s2f((short)q4.w);
            k[j][0] = s2f((short)k4.x); k[j][1] = s2f((short)k4.y);
            k[j][2] = s2f((short)k4.z); k[j][3] = s2f((short)k4.w);
            v[j][0] = s2f((short)v4.x); v[j][1] = s2f((short)v4.y);
            v[j][2] = s2f((short)v4.z); v[j][3] = s2f((short)v4.w);
        } else {
            #pragma unroll
            for (int c = 0; c < 4; ++c) { q[j][c] = 0.f; k[j][c] = 0.f; v[j][c] = 0.f; }
        }
    }
    float s[3][3];
    #pragma unroll
    for (int i = 0; i < 3; ++i)
        #pragma unroll
        for (int j = 0; j < 3; ++j)
            s[i][j] = q[i][0]*k[j][0] + q[i][1]*k[j][1] + q[i][2]*k[j][2] + q[i][3]*k[j][3];
    #pragma unroll
    for (int off = 32; off >= 1; off >>= 1)
        #pragma unroll
        for (int i = 0; i < 3; ++i)
            #pragma unroll
            for (int j = 0; j < 3; ++j)
                s[i][j] += __shfl_xor(s[i][j], off);
    const float scale = 0.07216878364870322f; // 1/sqrt(192)
    float p[3][3];
    #pragma unroll
    for (int i = 0; i < 3; ++i) {
        float mx = fmaxf(s[i][0], fmaxf(s[i][1], s[i][2])) * scale;
        float e0 = expf(s[i][0] * scale - mx);
        float e1 = expf(s[i][1] * scale - mx);
        float e2 = expf(s[i][2] * scale - mx);
        float inv = 1.0f / (e0 + e1 + e2);
        p[i][0] = e0 * inv; p[i][1] = e1 * inv; p[i][2] = e2 * inv;
    }
    if (act) {
        #pragma unroll
        for (int i = 0; i < 3; ++i) {
            bf16x4 o4;
            #pragma unroll
            for (int c = 0; c < 4; ++c)
                o4[c] = f2s(p[i][0]*v[0][c] + p[i][1]*v[1][c] + p[i][2]*v[2][c]);
            *(bf16x4*)(o + (size_t)(m * 3 + i) * DD + h * HDD + 4 * ln) = o4;
        }
    }
}

// ---------------- residual + LayerNorm (LN1): one WAVE per row, 4 rows/block ----------------
__global__ __launch_bounds__(256) void ln1_kernel(const bf16* __restrict__ xa,
                                                  const bf16* __restrict__ xb,
                                                  const float* __restrict__ gamma,
                                                  const float* __restrict__ beta,
                                                  bf16* __restrict__ out)
{
    const int r  = blockIdx.x * 4 + (threadIdx.x >> 6);
    const int ln = threadIdx.x & 63;
    const size_t rb = (size_t)r * DD;
    const int m = r / 3, i = r - m * 3;
    const int bb = m / NW, n = m - bb * NW;
    const size_t ab = (size_t)(bb * SS + n + i) * DD;
    const int e0 = ln * 8, e1 = 512 + ln * 4;
    bf16x8 a0 = *(const bf16x8*)(xa + ab + e0);
    bf16x8 b0 = *(const bf16x8*)(xb + rb + e0);
    bf16x4 a1 = *(const bf16x4*)(xa + ab + e1);
    bf16x4 b1 = *(const bf16x4*)(xb + rb + e1);
    float v[12];
    #pragma unroll
    for (int c = 0; c < 8; ++c) v[c] = s2f(a0[c]) + s2f(b0[c]);
    #pragma unroll
    for (int c = 0; c < 4; ++c) v[8 + c] = s2f(a1[c]) + s2f(b1[c]);
    float s1 = 0.f, s2 = 0.f;
    #pragma unroll
    for (int c = 0; c < 12; ++c) { s1 += v[c]; s2 += v[c] * v[c]; }
    #pragma unroll
    for (int off = 32; off >= 1; off >>= 1) {
        s1 += __shfl_xor(s1, off);
        s2 += __shfl_xor(s2, off);
    }
    const float mean = s1 * (1.0f / 768.0f);
    const float var  = fmaxf(s2 * (1.0f / 768.0f) - mean * mean, 0.0f);
    const float inv  = rsqrtf(var + 1e-5f);
    float4 g0 = *(const float4*)(gamma + e0);
    float4 g1 = *(const float4*)(gamma + e0 + 4);
    float4 g2 = *(const float4*)(gamma + e1);
    float4 t0 = *(const float4*)(beta + e0);
    float4 t1 = *(const float4*)(beta + e0 + 4);
    float4 t2 = *(const float4*)(beta + e1);
    const float gg[12] = {g0.x,g0.y,g0.z,g0.w,g1.x,g1.y,g1.z,g1.w,g2.x,g2.y,g2.z,g2.w};
    const float tt[12] = {t0.x,t0.y,t0.z,t0.w,t1.x,t1.y,t1.z,t1.w,t2.x,t2.y,t2.z,t2.w};
    bf16x8 o0; bf16x4 o1;
    #pragma unroll
    for (int c = 0; c < 8; ++c) o0[c] = f2s((v[c] - mean) * inv * gg[c] + tt[c]);
    #pragma unroll
    for (int c = 0; c < 4; ++c) o1[c] = f2s((v[8 + c] - mean) * inv * gg[8 + c] + tt[8 + c]);
    *(bf16x8*)(out + rb + e0) = o0;
    *(bf16x4*)(out + rb + e1) = o1;
}

// ---------------- fused residual + LN2 + max-pool + align + intent + window_num ----------------
__global__ __launch_bounds__(256) void ln2_pool_intent_kernel(
    const bf16* __restrict__ x, const bf16* __restrict__ f,
    const float* __restrict__ gamma, const float* __restrict__ beta,
    const float* __restrict__ iw, const float* __restrict__ ib,
    const int* __restrict__ seq,
    float* __restrict__ pred, float* __restrict__ align, float* __restrict__ wn_out)
{
    const int m  = blockIdx.x;
    const int bb = m / NW, n = m - bb * NW;
    const int wv = threadIdx.x >> 6, ln = threadIdx.x & 63;
    __shared__ float vsh[3][DD];
    __shared__ float pl[DD];
    if (wv < 3) {
        const size_t rb = (size_t)(m * 3 + wv) * DD;
        const int e0 = ln * 8, e1 = 512 + ln * 4;
        bf16x8 a0 = *(const bf16x8*)(x + rb + e0);
        bf16x8 b0 = *(const bf16x8*)(f + rb + e0);
        bf16x4 a1 = *(const bf16x4*)(x + rb + e1);
        bf16x4 b1 = *(const bf16x4*)(f + rb + e1);
        float v[12];
        #pragma unroll
        for (int c = 0; c < 8; ++c) v[c] = s2f(a0[c]) + s2f(b0[c]);
        #pragma unroll
        for (int c = 0; c < 4; ++c) v[8 + c] = s2f(a1[c]) + s2f(b1[c]);
        float s1 = 0.f, s2 = 0.f;
        #pragma unroll
        for (int c = 0; c < 12; ++c) { s1 += v[c]; s2 += v[c] * v[c]; }
        #pragma unroll
        for (int off = 32; off >= 1; off >>= 1) {
            s1 += __shfl_xor(s1, off);
            s2 += __shfl_xor(s2, off);
        }
        const float mean = s1 * (1.0f / 768.0f);
        const float var  = fmaxf(s2 * (1.0f / 768.0f) - mean * mean, 0.0f);
        const float inv  = rsqrtf(var + 1e-5f);
        float4 g0 = *(const float4*)(gamma + e0);
        float4 g1 = *(const float4*)(gamma + e0 + 4);
        float4 g2 = *(const float4*)(gamma + e1);
        float4 t0 = *(const float4*)(beta + e0);
        float4 t1 = *(const float4*)(beta + e0 + 4);
        float4 t2 = *(const float4*)(beta + e1);
        const float gg[12] = {g0.x,g0.y,g0.z,g0.w,g1.x,g1.y,g1.z,g1.w,g2.x,g2.y,g2.z,g2.w};
        const float tt[12] = {t0.x,t0.y,t0.z,t0.w,t1.x,t1.y,t1.z,t1.w,t2.x,t2.y,t2.z,t2.w};
        #pragma unroll
        for (int c = 0; c < 8; ++c) vsh[wv][e0 + c] = (v[c] - mean) * inv * gg[c] + tt[c];
        #pragma unroll
        for (int c = 0; c < 4; ++c) vsh[wv][e1 + c] = (v[8 + c] - mean) * inv * gg[8 + c] + tt[8 + c];
    }
    __syncthreads();
    const size_t ab = (size_t)bb * 512 * DD;
    #pragma unroll
    for (int t = 0; t < 3; ++t) {
        const int d = threadIdx.x + t * 256;
        float mx = fmaxf(vsh[0][d], fmaxf(vsh[1][d], vsh[2][d]));
        pl[d] = mx;
        align[ab + (size_t)(n + 1) * DD + d] = mx;
        if (n == 0)      align[ab + d] = mx;
        if (n == NW - 1) align[ab + (size_t)511 * DD + d] = mx;
    }
    if (m == 0 && threadIdx.x < BB) {
        int wn = seq[threadIdx.x] - 2;
        if (wn < 1) wn = 1;
        wn_out[threadIdx.x] = (float)wn;
    }
    __syncthreads();
    for (int c = wv; c < NID; c += 4) {
        float sum = 0.0f;
        #pragma unroll
        for (int t = 0; t < 12; ++t) {
            const int d = ln + t * 64;
            sum += pl[d] * iw[(size_t)c * DD + d];
        }
        #pragma unroll
        for (int off = 32; off >= 1; off >>= 1)
            sum += __shfl_xor(sum, off);
        if (ln == 0) pred[(size_t)m * NID + c] = sum + ib[c];
    }
}

extern "C" void kernel_launch(void* const* d_in, const int* in_sizes, int n_in,
                              void* d_out, int out_size, void* d_ws, size_t ws_size,
                              hipStream_t stream)
{
    const float* hidden   = (const float*)d_in[0];
    const int*   seq_lens = (const int*)d_in[1];
    const float* in_w     = (const float*)d_in[2];
    const float* in_b     = (const float*)d_in[3];
    const float* out_w    = (const float*)d_in[4];
    const float* out_b    = (const float*)d_in[5];
    const float* ln1_g    = (const float*)d_in[6];
    const float* ln1_bb   = (const float*)d_in[7];
    const float* ln2_g    = (const float*)d_in[8];
    const float* ln2_bb   = (const float*)d_in[9];
    const float* f1_w     = (const float*)d_in[10];
    const float* f1_b     = (const float*)d_in[11];
    const float* f2_w     = (const float*)d_in[12];
    const float* f2_b     = (const float*)d_in[13];
    const float* it_w     = (const float*)d_in[14];
    const float* it_b     = (const float*)d_in[15];

    // ---- compact workspace layout (liveness-based reuse) ----
    char* ws = (char*)d_ws;
    bf16*  hid_bf   = (bf16*)(ws + 0);          // 12,582,912 B
    bf16*  win_bf   = (bf16*)(ws + 12582912);   //  3,538,944
    bf16*  wout_bf  = (bf16*)(ws + 16121856);   //  1,179,648
    bf16*  wf1_bf   = (bf16*)(ws + 17301504);   //  3,145,728
    bf16*  wf2_bf   = (bf16*)(ws + 20447232);   //  3,145,728
    bf16*  qkv_bf   = (bf16*)(ws + 23592960);   // R1: qkv -> oproj -> f
    bf16*  oproj_bf = qkv_bf;
    bf16*  f_bf     = qkv_bf;
    bf16*  o_bf     = (bf16*)(ws + 61341696);   // R2: o
    bf16*  x_bf     = (bf16*)(ws + 98942976);   // R3
    const size_t H_BASE = 136544256ull;
    bf16*  h_bf     = (bf16*)(ws + H_BASE);     // FFN hidden (chunked vs ws_size)

    float* out_pred  = (float*)d_out;           // 146880
    float* out_wn    = out_pred + 146880;       // 16
    float* out_align = out_pred + 146896;       // 6,291,456

    // single fused f32 -> bf16 pass for all 5 tensors
    cvt_all_kernel<<<2048, 256, 0, stream>>>(
        (const float4*)hidden, (ushort4*)hid_bf,
        (const float4*)in_w,   (ushort4*)win_bf,
        (const float4*)out_w,  (ushort4*)wout_bf,
        (const float4*)f1_w,   (ushort4*)wf1_bf,
        (const float4*)f2_w,   (ushort4*)wf2_bf);

    // QKV (per-position, shared across windows): [8192,768] x [2304,768]^T  (BK=64 128²)
    gemm_bt<false><<<18 * 64, 256, 0, stream>>>(hid_bf, win_bf, in_b, qkv_bf,
                                                8192, 2304, 768, 18);
    // attention per (window, head)
    attn_kernel<<<NWIN, 256, 0, stream>>>(qkv_bf, o_bf);
    // out_proj: [24480,768] x [768,768]^T  (BK=64 128²; writes R1, qkv dead)
    gemm_bt<false><<<6 * 192, 256, 0, stream>>>(o_bf, wout_bf, out_b, oproj_bf,
                                                MR, 768, 768, 6);
    // x = LN1(win + oproj)  (wave-per-row)
    ln1_kernel<<<MR / 4, 256, 0, stream>>>(hid_bf, oproj_bf, ln1_g, ln1_bb, x_bf);

    // FFN, chunked over rows so the 2048-wide hidden fits in remaining workspace.
    size_t avail = ws_size > H_BASE ? ws_size - H_BASE : 0;
    long cap = (long)(avail / (DFFD * 2));
    cap = (cap / 128) * 128;
    if (cap < 128) cap = 128;
    if (cap > MR) cap = MR;
    for (int r0 = 0; r0 < MR; r0 += (int)cap) {
        int mc = MR - r0; if (mc > cap) mc = (int)cap;
        int mt128 = (mc + 127) / 128;
        // FFN1: rows x [2048,768]^T + ReLU  (BK=64 128²)
        gemm_bt<true><<<mt128 * 16, 256, 0, stream>>>(x_bf + (size_t)r0 * DD, wf1_bf, f1_b, h_bf,
                                                      mc, DFFD, 768, 16);
        // FFN2: rows x [768,2048]^T  (BK=64 128²; writes f into R1, oproj dead)
        gemm_bt<false><<<mt128 * 6, 256, 0, stream>>>(h_bf, wf2_bf, f2_b,
                                                      f_bf + (size_t)r0 * DD,
                                                      mc, 768, DFFD, 6);
    }

    // fused residual + LN2 + max-pool + align + intent + window_num
    ln2_pool_intent_kernel<<<NWIN, 256, 0, stream>>>(x_bf, f_bf, ln2_g, ln2_bb, it_w, it_b,
                                                     seq_lens, out_pred, out_align, out_wn);
}

// Round 14
// 330.127 us; speedup vs baseline: 4.1094x; 1.1443x over previous
//
#include <hip/hip_runtime.h>
#include <hip/hip_bf16.h>

#define BB   16
#define SS   512
#define DD   768
#define NHH  4
#define HDD  192
#define DFFD 2048
#define NID  18
#define NW   510          // S - W + 1
#define NWIN (BB * NW)    // 8160 windows
#define MR   (NWIN * 3)   // 24480 encoder rows

typedef __attribute__((ext_vector_type(8))) short bf16x8;
typedef __attribute__((ext_vector_type(4))) short bf16x4;
typedef __attribute__((ext_vector_type(4))) float f32x4;
typedef __hip_bfloat16 bf16;

__device__ __forceinline__ float b2f(bf16 x) { return __bfloat162float(x); }
__device__ __forceinline__ float s2f(short s) {
    return __bfloat162float(__builtin_bit_cast(bf16, (unsigned short)s));
}
__device__ __forceinline__ short f2s(float f) {
    return (short)__builtin_bit_cast(unsigned short, __float2bfloat16(f));
}

// ---------------- fused f32 -> bf16/fp8 conversion for all 5 tensors ----------------
__device__ __forceinline__ void cvt_range(const float4* __restrict__ in,
                                          ushort4* __restrict__ out, int i)
{
    float4 f = in[i];
    ushort4 u;
    u.x = __builtin_bit_cast(unsigned short, __float2bfloat16(f.x));
    u.y = __builtin_bit_cast(unsigned short, __float2bfloat16(f.y));
    u.z = __builtin_bit_cast(unsigned short, __float2bfloat16(f.z));
    u.w = __builtin_bit_cast(unsigned short, __float2bfloat16(f.w));
    out[i] = u;
}
__device__ __forceinline__ void cvt_range_f8(const float4* __restrict__ in,
                                             unsigned int* __restrict__ out, int i)
{
    float4 f = in[i];
    int p = 0;
    p = __builtin_amdgcn_cvt_pk_fp8_f32(f.x, f.y, p, false);
    p = __builtin_amdgcn_cvt_pk_fp8_f32(f.z, f.w, p, true);
    out[i] = (unsigned int)p;
}

#define CN0 1572864   // hidden
#define CN1 442368    // in_proj_w
#define CN2 147456    // out_proj_w
#define CN3 393216    // ffn_w1  (-> fp8)
#define CN4 393216    // ffn_w2  (-> fp8)
#define CT  (CN0 + CN1 + CN2 + CN3 + CN4)

__global__ __launch_bounds__(256) void cvt_all_kernel(
    const float4* __restrict__ s0, ushort4* __restrict__ d0,
    const float4* __restrict__ s1, ushort4* __restrict__ d1,
    const float4* __restrict__ s2, ushort4* __restrict__ d2,
    const float4* __restrict__ s3, unsigned int* __restrict__ d3,
    const float4* __restrict__ s4, unsigned int* __restrict__ d4)
{
    for (int i = blockIdx.x * 256 + threadIdx.x; i < CT; i += gridDim.x * 256) {
        int j = i;
        if (j < CN0) { cvt_range(s0, d0, j); continue; }
        j -= CN0;
        if (j < CN1) { cvt_range(s1, d1, j); continue; }
        j -= CN1;
        if (j < CN2) { cvt_range(s2, d2, j); continue; }
        j -= CN2;
        if (j < CN3) { cvt_range_f8(s3, d3, j); continue; }
        j -= CN3;
        cvt_range_f8(s4, d4, j);
    }
}

// ---------------- 128x128 bf16 NT GEMM, BK=64, swizzled LDS ----------------
// VERIFIED round 11/13. Do NOT add sched_barrier fences / same-buffer prefetch
// (round 12: scratch spills, 3.6x regression).
template<bool RELU>
__global__ void gemm_bt(const bf16* __restrict__ A, const bf16* __restrict__ Bm,
                        const float* __restrict__ bias, bf16* __restrict__ C,
                        int M, int N, int K, int nx)
{
    __shared__ __align__(16) char smem[32768];
    char* smemc = smem;

    const int nwg  = gridDim.x;
    const int orig = blockIdx.x;
    const int xcd  = orig & 7;
    const int idx  = orig >> 3;
    const int q8   = nwg >> 3, r8 = nwg & 7;
    const int newid = (xcd < r8 ? xcd * (q8 + 1) : r8 * (q8 + 1) + (xcd - r8) * q8) + idx;
    const int row0 = (newid / nx) * 128;
    const int col0 = (newid % nx) * 128;

    const int tid = threadIdx.x;
    const int ln  = tid & 63;
    const int wv  = tid >> 6;
    const int wm = (wv >> 1) * 64;
    const int wn = (wv & 1) * 64;
    const int lrow  = ln & 15;
    const int kslot = ln >> 4;
    const int xk0 = (kslot * 16)      ^ ((lrow & 7) << 4);
    const int xk1 = (64 + kslot * 16) ^ ((lrow & 7) << 4);

    const int srow = ln >> 3;
    const int ce   = ((ln & 7) ^ srow) * 8;
    const int rb8  = wv * 32 + srow;
    const bf16* pA[4];
    const bf16* pB[4];
    #pragma unroll
    for (int i = 0; i < 4; ++i) {
        int ar = row0 + rb8 + i * 8;
        if (ar > M - 1) ar = M - 1;
        pA[i] = A  + (size_t)ar * K + ce;
        pB[i] = Bm + (size_t)(col0 + rb8 + i * 8) * K + ce;
    }

    f32x4 acc[4][4] = {};

    for (int k0 = 0; k0 < K; k0 += 64) {
        #pragma unroll
        for (int i = 0; i < 4; ++i) {
            __builtin_amdgcn_global_load_lds(
                (const __attribute__((address_space(1))) void*)(pA[i] + k0),
                (__attribute__((address_space(3))) void*)(smemc + wv * 4096 + i * 1024), 16, 0, 0);
            __builtin_amdgcn_global_load_lds(
                (const __attribute__((address_space(1))) void*)(pB[i] + k0),
                (__attribute__((address_space(3))) void*)(smemc + 16384 + wv * 4096 + i * 1024), 16, 0, 0);
        }
        __syncthreads();
        bf16x8 a0[4], a1[4], b0[4], b1[4];
        #pragma unroll
        for (int mi = 0; mi < 4; ++mi) {
            const int rb = (wm + mi * 16 + lrow) * 128;
            a0[mi] = *(const bf16x8*)(smemc + rb + xk0);
            a1[mi] = *(const bf16x8*)(smemc + rb + xk1);
        }
        #pragma unroll
        for (int ni = 0; ni < 4; ++ni) {
            const int rb = 16384 + (wn + ni * 16 + lrow) * 128;
            b0[ni] = *(const bf16x8*)(smemc + rb + xk0);
            b1[ni] = *(const bf16x8*)(smemc + rb + xk1);
        }
        #pragma unroll
        for (int mi = 0; mi < 4; ++mi)
            #pragma unroll
            for (int ni = 0; ni < 4; ++ni) {
                acc[mi][ni] = __builtin_amdgcn_mfma_f32_16x16x32_bf16(a0[mi], b0[ni], acc[mi][ni], 0, 0, 0);
                acc[mi][ni] = __builtin_amdgcn_mfma_f32_16x16x32_bf16(a1[mi], b1[ni], acc[mi][ni], 0, 0, 0);
            }
        __syncthreads();
    }

    #pragma unroll
    for (int mi = 0; mi < 4; ++mi) {
        #pragma unroll
        for (int ni = 0; ni < 4; ++ni) {
            const int col = col0 + wn + ni * 16 + lrow;
            const float bb = bias[col];
            #pragma unroll
            for (int r = 0; r < 4; ++r) {
                const int row = row0 + wm + mi * 16 + (ln >> 4) * 4 + r;
                if (row < M) {
                    float v = acc[mi][ni][r] + bb;
                    if (RELU) v = fmaxf(v, 0.0f);
                    C[(size_t)row * N + col] = __float2bfloat16(v);
                }
            }
        }
    }
}

// ---------------- 128x128 FP8 NT GEMM, BK=128 (same byte geometry as bf16 BK=64) ----
// A,B are fp8 e4m3 [rows][K]. LDS [128 rows][128 B] per operand, same staging
// chunks + XOR swizzle as gemm_bt (bytes identical). Each K-tile = 128 fp8 elems
// = 4 sub-tiles of K=32 for mfma_f32_16x16x32_fp8_fp8 (8B frags). 2x FLOP per
// LDS byte and per stage-drain vs bf16. OUT8: pack output to fp8 (for h).
template<bool RELU, bool OUT8>
__global__ void gemm_f8(const unsigned char* __restrict__ A, const unsigned char* __restrict__ Bm,
                        const float* __restrict__ bias, void* __restrict__ Cv,
                        int M, int N, int K, int nx)
{
    __shared__ __align__(16) char smem[32768];
    char* smemc = smem;

    const int nwg  = gridDim.x;
    const int orig = blockIdx.x;
    const int xcd  = orig & 7;
    const int idx  = orig >> 3;
    const int q8   = nwg >> 3, r8 = nwg & 7;
    const int newid = (xcd < r8 ? xcd * (q8 + 1) : r8 * (q8 + 1) + (xcd - r8) * q8) + idx;
    const int row0 = (newid / nx) * 128;
    const int col0 = (newid % nx) * 128;

    const int tid = threadIdx.x;
    const int ln  = tid & 63;
    const int wv  = tid >> 6;
    const int wm = (wv >> 1) * 64;
    const int wn = (wv & 1) * 64;
    const int lrow  = ln & 15;
    const int kslot = ln >> 4;       // k-group within K=32 sub-tile (8 fp8 = 8B)

    // per-sub-tile swizzled byte offsets within a row (t = 0..3)
    int off8[4];
    #pragma unroll
    for (int t = 0; t < 4; ++t)
        off8[t] = (((t * 2 + (kslot >> 1)) ^ (lrow & 7)) << 4) + (kslot & 1) * 8;

    // staging: identical byte pattern to gemm_bt; 16B chunk = 16 fp8 elems
    const int srow = ln >> 3;
    const int ce   = ((ln & 7) ^ srow) * 16;     // element (=byte) offset
    const int rb8  = wv * 32 + srow;
    const unsigned char* pA[4];
    const unsigned char* pB[4];
    #pragma unroll
    for (int i = 0; i < 4; ++i) {
        int ar = row0 + rb8 + i * 8;
        if (ar > M - 1) ar = M - 1;
        pA[i] = A  + (size_t)ar * K + ce;
        pB[i] = Bm + (size_t)(col0 + rb8 + i * 8) * K + ce;
    }

    f32x4 acc[4][4] = {};

    for (int k0 = 0; k0 < K; k0 += 128) {
        #pragma unroll
        for (int i = 0; i < 4; ++i) {
            __builtin_amdgcn_global_load_lds(
                (const __attribute__((address_space(1))) void*)(pA[i] + k0),
                (__attribute__((address_space(3))) void*)(smemc + wv * 4096 + i * 1024), 16, 0, 0);
            __builtin_amdgcn_global_load_lds(
                (const __attribute__((address_space(1))) void*)(pB[i] + k0),
                (__attribute__((address_space(3))) void*)(smemc + 16384 + wv * 4096 + i * 1024), 16, 0, 0);
        }
        __syncthreads();
        #pragma unroll
        for (int t = 0; t < 4; ++t) {
            long long a[4], b[4];
            #pragma unroll
            for (int mi = 0; mi < 4; ++mi)
                a[mi] = *(const long long*)(smemc + (wm + mi * 16 + lrow) * 128 + off8[t]);
            #pragma unroll
            for (int ni = 0; ni < 4; ++ni)
                b[ni] = *(const long long*)(smemc + 16384 + (wn + ni * 16 + lrow) * 128 + off8[t]);
            #pragma unroll
            for (int mi = 0; mi < 4; ++mi)
                #pragma unroll
                for (int ni = 0; ni < 4; ++ni)
                    acc[mi][ni] = __builtin_amdgcn_mfma_f32_16x16x32_fp8_fp8(a[mi], b[ni], acc[mi][ni], 0, 0, 0);
        }
        __syncthreads();
    }

    #pragma unroll
    for (int mi = 0; mi < 4; ++mi) {
        #pragma unroll
        for (int ni = 0; ni < 4; ++ni) {
            const int col = col0 + wn + ni * 16 + lrow;
            const float bb = bias[col];
            #pragma unroll
            for (int r = 0; r < 4; ++r) {
                const int row = row0 + wm + mi * 16 + (ln >> 4) * 4 + r;
                if (row < M) {
                    float v = acc[mi][ni][r] + bb;
                    if (RELU) v = fmaxf(v, 0.0f);
                    if (OUT8) {
                        int p = __builtin_amdgcn_cvt_pk_fp8_f32(v, v, 0, false);
                        ((unsigned char*)Cv)[(size_t)row * N + col] = (unsigned char)p;
                    } else {
                        ((bf16*)Cv)[(size_t)row * N + col] = __float2bfloat16(v);
                    }
                }
            }
        }
    }
}

// ---------------- attention over W=3 per (window, head): one wave each ----------------
__global__ __launch_bounds__(256) void attn_kernel(const bf16* __restrict__ qkv, bf16* __restrict__ o)
{
    const int m  = blockIdx.x;
    const int h  = threadIdx.x >> 6;
    const int ln = threadIdx.x & 63;
    const int bb = m / NW, n = m - bb * NW;
    const bool act = ln < 48;
    const size_t base = (size_t)(bb * SS + n) * (3 * DD) + h * HDD + 4 * ln;
    float q[3][4], k[3][4], v[3][4];
    #pragma unroll
    for (int j = 0; j < 3; ++j) {
        if (act) {
            const size_t idx = base + (size_t)j * (3 * DD);
            ushort4 q4 = *(const ushort4*)(qkv + idx);
            ushort4 k4 = *(const ushort4*)(qkv + idx + DD);
            ushort4 v4 = *(const ushort4*)(qkv + idx + 2 * DD);
            q[j][0] = s2f((short)q4.x); q[j][1] = s2f((short)q4.y);
            q[j][2] = s2f((short)q4.z); q[j][3] = s2f((short)q4.w);
            k[j][0] = s2f((short)k4.x); k[j][1] = s2f((short)k4.y);
            k[j][2] = s2f((short)k4.z); k[j][3] = s2f((short)k4.w);
            v[j][0] = s2f((short)v4.x); v[j][1] = s2f((short)v4.y);
            v[j][2] = s2f((short)v4.z); v[j][3] = s2f((short)v4.w);
        } else {
            #pragma unroll
            for (int c = 0; c < 4; ++c) { q[j][c] = 0.f; k[j][c] = 0.f; v[j][c] = 0.f; }
        }
    }
    float s[3][3];
    #pragma unroll
    for (int i = 0; i < 3; ++i)
        #pragma unroll
        for (int j = 0; j < 3; ++j)
            s[i][j] = q[i][0]*k[j][0] + q[i][1]*k[j][1] + q[i][2]*k[j][2] + q[i][3]*k[j][3];
    #pragma unroll
    for (int off = 32; off >= 1; off >>= 1)
        #pragma unroll
        for (int i = 0; i < 3; ++i)
            #pragma unroll
            for (int j = 0; j < 3; ++j)
                s[i][j] += __shfl_xor(s[i][j], off);
    const float scale = 0.07216878364870322f; // 1/sqrt(192)
    float p[3][3];
    #pragma unroll
    for (int i = 0; i < 3; ++i) {
        float mx = fmaxf(s[i][0], fmaxf(s[i][1], s[i][2])) * scale;
        float e0 = expf(s[i][0] * scale - mx);
        float e1 = expf(s[i][1] * scale - mx);
        float e2 = expf(s[i][2] * scale - mx);
        float inv = 1.0f / (e0 + e1 + e2);
        p[i][0] = e0 * inv; p[i][1] = e1 * inv; p[i][2] = e2 * inv;
    }
    if (act) {
        #pragma unroll
        for (int i = 0; i < 3; ++i) {
            bf16x4 o4;
            #pragma unroll
            for (int c = 0; c < 4; ++c)
                o4[c] = f2s(p[i][0]*v[0][c] + p[i][1]*v[1][c] + p[i][2]*v[2][c]);
            *(bf16x4*)(o + (size_t)(m * 3 + i) * DD + h * HDD + 4 * ln) = o4;
        }
    }
}

// ---------------- residual + LN1: wave-per-row; emits bf16 x AND fp8 x ----------------
__global__ __launch_bounds__(256) void ln1_kernel(const bf16* __restrict__ xa,
                                                  const bf16* __restrict__ xb,
                                                  const float* __restrict__ gamma,
                                                  const float* __restrict__ beta,
                                                  bf16* __restrict__ out,
                                                  unsigned char* __restrict__ out8)
{
    const int r  = blockIdx.x * 4 + (threadIdx.x >> 6);
    const int ln = threadIdx.x & 63;
    const size_t rb = (size_t)r * DD;
    const int m = r / 3, i = r - m * 3;
    const int bb = m / NW, n = m - bb * NW;
    const size_t ab = (size_t)(bb * SS + n + i) * DD;
    const int e0 = ln * 8, e1 = 512 + ln * 4;
    bf16x8 a0 = *(const bf16x8*)(xa + ab + e0);
    bf16x8 b0 = *(const bf16x8*)(xb + rb + e0);
    bf16x4 a1 = *(const bf16x4*)(xa + ab + e1);
    bf16x4 b1 = *(const bf16x4*)(xb + rb + e1);
    float v[12];
    #pragma unroll
    for (int c = 0; c < 8; ++c) v[c] = s2f(a0[c]) + s2f(b0[c]);
    #pragma unroll
    for (int c = 0; c < 4; ++c) v[8 + c] = s2f(a1[c]) + s2f(b1[c]);
    float s1 = 0.f, s2 = 0.f;
    #pragma unroll
    for (int c = 0; c < 12; ++c) { s1 += v[c]; s2 += v[c] * v[c]; }
    #pragma unroll
    for (int off = 32; off >= 1; off >>= 1) {
        s1 += __shfl_xor(s1, off);
        s2 += __shfl_xor(s2, off);
    }
    const float mean = s1 * (1.0f / 768.0f);
    const float var  = fmaxf(s2 * (1.0f / 768.0f) - mean * mean, 0.0f);
    const float inv  = rsqrtf(var + 1e-5f);
    float4 g0 = *(const float4*)(gamma + e0);
    float4 g1 = *(const float4*)(gamma + e0 + 4);
    float4 g2 = *(const float4*)(gamma + e1);
    float4 t0 = *(const float4*)(beta + e0);
    float4 t1 = *(const float4*)(beta + e0 + 4);
    float4 t2 = *(const float4*)(beta + e1);
    const float gg[12] = {g0.x,g0.y,g0.z,g0.w,g1.x,g1.y,g1.z,g1.w,g2.x,g2.y,g2.z,g2.w};
    const float tt[12] = {t0.x,t0.y,t0.z,t0.w,t1.x,t1.y,t1.z,t1.w,t2.x,t2.y,t2.z,t2.w};
    float o_[12];
    #pragma unroll
    for (int c = 0; c < 12; ++c) o_[c] = (v[c] - mean) * inv * gg[c] + tt[c];
    bf16x8 o0; bf16x4 o1;
    #pragma unroll
    for (int c = 0; c < 8; ++c) o0[c] = f2s(o_[c]);
    #pragma unroll
    for (int c = 0; c < 4; ++c) o1[c] = f2s(o_[8 + c]);
    *(bf16x8*)(out + rb + e0) = o0;
    *(bf16x4*)(out + rb + e1) = o1;
    int p0 = 0, p1 = 0, p2 = 0;
    p0 = __builtin_amdgcn_cvt_pk_fp8_f32(o_[0], o_[1], p0, false);
    p0 = __builtin_amdgcn_cvt_pk_fp8_f32(o_[2], o_[3], p0, true);
    p1 = __builtin_amdgcn_cvt_pk_fp8_f32(o_[4], o_[5], p1, false);
    p1 = __builtin_amdgcn_cvt_pk_fp8_f32(o_[6], o_[7], p1, true);
    p2 = __builtin_amdgcn_cvt_pk_fp8_f32(o_[8], o_[9], p2, false);
    p2 = __builtin_amdgcn_cvt_pk_fp8_f32(o_[10], o_[11], p2, true);
    *(unsigned int*)(out8 + rb + e0)     = (unsigned int)p0;
    *(unsigned int*)(out8 + rb + e0 + 4) = (unsigned int)p1;
    *(unsigned int*)(out8 + rb + e1)     = (unsigned int)p2;
}

// ---------------- fused residual + LN2 + max-pool + align + intent + window_num ----------------
__global__ __launch_bounds__(256) void ln2_pool_intent_kernel(
    const bf16* __restrict__ x, const bf16* __restrict__ f,
    const float* __restrict__ gamma, const float* __restrict__ beta,
    const float* __restrict__ iw, const float* __restrict__ ib,
    const int* __restrict__ seq,
    float* __restrict__ pred, float* __restrict__ align, float* __restrict__ wn_out)
{
    const int m  = blockIdx.x;
    const int bb = m / NW, n = m - bb * NW;
    const int wv = threadIdx.x >> 6, ln = threadIdx.x & 63;
    __shared__ float vsh[3][DD];
    __shared__ float pl[DD];
    if (wv < 3) {
        const size_t rb = (size_t)(m * 3 + wv) * DD;
        const int e0 = ln * 8, e1 = 512 + ln * 4;
        bf16x8 a0 = *(const bf16x8*)(x + rb + e0);
        bf16x8 b0 = *(const bf16x8*)(f + rb + e0);
        bf16x4 a1 = *(const bf16x4*)(x + rb + e1);
        bf16x4 b1 = *(const bf16x4*)(f + rb + e1);
        float v[12];
        #pragma unroll
        for (int c = 0; c < 8; ++c) v[c] = s2f(a0[c]) + s2f(b0[c]);
        #pragma unroll
        for (int c = 0; c < 4; ++c) v[8 + c] = s2f(a1[c]) + s2f(b1[c]);
        float s1 = 0.f, s2 = 0.f;
        #pragma unroll
        for (int c = 0; c < 12; ++c) { s1 += v[c]; s2 += v[c] * v[c]; }
        #pragma unroll
        for (int off = 32; off >= 1; off >>= 1) {
            s1 += __shfl_xor(s1, off);
            s2 += __shfl_xor(s2, off);
        }
        const float mean = s1 * (1.0f / 768.0f);
        const float var  = fmaxf(s2 * (1.0f / 768.0f) - mean * mean, 0.0f);
        const float inv  = rsqrtf(var + 1e-5f);
        float4 g0 = *(const float4*)(gamma + e0);
        float4 g1 = *(const float4*)(gamma + e0 + 4);
        float4 g2 = *(const float4*)(gamma + e1);
        float4 t0 = *(const float4*)(beta + e0);
        float4 t1 = *(const float4*)(beta + e0 + 4);
        float4 t2 = *(const float4*)(beta + e1);
        const float gg[12] = {g0.x,g0.y,g0.z,g0.w,g1.x,g1.y,g1.z,g1.w,g2.x,g2.y,g2.z,g2.w};
        const float tt[12] = {t0.x,t0.y,t0.z,t0.w,t1.x,t1.y,t1.z,t1.w,t2.x,t2.y,t2.z,t2.w};
        #pragma unroll
        for (int c = 0; c < 8; ++c) vsh[wv][e0 + c] = (v[c] - mean) * inv * gg[c] + tt[c];
        #pragma unroll
        for (int c = 0; c < 4; ++c) vsh[wv][e1 + c] = (v[8 + c] - mean) * inv * gg[8 + c] + tt[8 + c];
    }
    __syncthreads();
    const size_t ab = (size_t)bb * 512 * DD;
    #pragma unroll
    for (int t = 0; t < 3; ++t) {
        const int d = threadIdx.x + t * 256;
        float mx = fmaxf(vsh[0][d], fmaxf(vsh[1][d], vsh[2][d]));
        pl[d] = mx;
        align[ab + (size_t)(n + 1) * DD + d] = mx;
        if (n == 0)      align[ab + d] = mx;
        if (n == NW - 1) align[ab + (size_t)511 * DD + d] = mx;
    }
    if (m == 0 && threadIdx.x < BB) {
        int wn = seq[threadIdx.x] - 2;
        if (wn < 1) wn = 1;
        wn_out[threadIdx.x] = (float)wn;
    }
    __syncthreads();
    for (int c = wv; c < NID; c += 4) {
        float sum = 0.0f;
        #pragma unroll
        for (int t = 0; t < 12; ++t) {
            const int d = ln + t * 64;
            sum += pl[d] * iw[(size_t)c * DD + d];
        }
        #pragma unroll
        for (int off = 32; off >= 1; off >>= 1)
            sum += __shfl_xor(sum, off);
        if (ln == 0) pred[(size_t)m * NID + c] = sum + ib[c];
    }
}

extern "C" void kernel_launch(void* const* d_in, const int* in_sizes, int n_in,
                              void* d_out, int out_size, void* d_ws, size_t ws_size,
                              hipStream_t stream)
{
    const float* hidden   = (const float*)d_in[0];
    const int*   seq_lens = (const int*)d_in[1];
    const float* in_w     = (const float*)d_in[2];
    const float* in_b     = (const float*)d_in[3];
    const float* out_w    = (const float*)d_in[4];
    const float* out_b    = (const float*)d_in[5];
    const float* ln1_g    = (const float*)d_in[6];
    const float* ln1_bb   = (const float*)d_in[7];
    const float* ln2_g    = (const float*)d_in[8];
    const float* ln2_bb   = (const float*)d_in[9];
    const float* f1_w     = (const float*)d_in[10];
    const float* f1_b     = (const float*)d_in[11];
    const float* f2_w     = (const float*)d_in[12];
    const float* f2_b     = (const float*)d_in[13];
    const float* it_w     = (const float*)d_in[14];
    const float* it_b     = (const float*)d_in[15];

    // ---- workspace layout (ws >= 236.8 MB proven by round-10 unchunked run) ----
    char* ws = (char*)d_ws;
    bf16*          hid_bf  = (bf16*)(ws + 0);          // 12,582,912 B
    bf16*          win_bf  = (bf16*)(ws + 12582912);   //  3,538,944
    bf16*          wout_bf = (bf16*)(ws + 16121856);   //  1,179,648
    unsigned char* wf1_f8  = (unsigned char*)(ws + 17301504);   // 1,572,864
    unsigned char* wf2_f8  = (unsigned char*)(ws + 18874368);   // 1,572,864
    bf16*          qkv_bf  = (bf16*)(ws + 23592960);   // R1: qkv -> oproj -> f
    bf16*          oproj_bf= qkv_bf;
    bf16*          f_bf    = qkv_bf;
    bf16*          o_bf    = (bf16*)(ws + 61341696);   // R2: o
    bf16*          x_bf    = (bf16*)(ws + 98942976);   // R3  (ends 136,544,256)
    unsigned char* x_f8    = (unsigned char*)(ws + 136544256);  // 18,800,640
    unsigned char* h_f8    = (unsigned char*)(ws + 155344896);  // 50,135,040 (ends 205.5 MB)

    float* out_pred  = (float*)d_out;           // 146880
    float* out_wn    = out_pred + 146880;       // 16
    float* out_align = out_pred + 146896;       // 6,291,456

    // fused f32 -> bf16 (hidden, in_w, out_w) + f32 -> fp8 (ffn_w1, ffn_w2)
    cvt_all_kernel<<<2048, 256, 0, stream>>>(
        (const float4*)hidden, (ushort4*)hid_bf,
        (const float4*)in_w,   (ushort4*)win_bf,
        (const float4*)out_w,  (ushort4*)wout_bf,
        (const float4*)f1_w,   (unsigned int*)wf1_f8,
        (const float4*)f2_w,   (unsigned int*)wf2_f8);

    // QKV: [8192,768] x [2304,768]^T  (bf16 BK=64 128²)
    gemm_bt<false><<<18 * 64, 256, 0, stream>>>(hid_bf, win_bf, in_b, qkv_bf,
                                                8192, 2304, 768, 18);
    // attention per (window, head)
    attn_kernel<<<NWIN, 256, 0, stream>>>(qkv_bf, o_bf);
    // out_proj: [24480,768] x [768,768]^T  (bf16; writes R1, qkv dead)
    gemm_bt<false><<<6 * 192, 256, 0, stream>>>(o_bf, wout_bf, out_b, oproj_bf,
                                                MR, 768, 768, 6);
    // x = LN1(win + oproj): bf16 x (residual/tail) + fp8 x (FFN1 input)
    ln1_kernel<<<MR / 4, 256, 0, stream>>>(hid_bf, oproj_bf, ln1_g, ln1_bb, x_bf, x_f8);

    // FFN1: [24480,768] x [2048,768]^T + ReLU -> fp8 h  (fp8 BK=128 128²)
    gemm_f8<true, true><<<192 * 16, 256, 0, stream>>>(x_f8, wf1_f8, f1_b, h_f8,
                                                      MR, DFFD, 768, 16);
    // FFN2: [24480,2048] x [768,2048]^T -> bf16 f (into R1, oproj dead)
    gemm_f8<false, false><<<192 * 6, 256, 0, stream>>>(h_f8, wf2_f8, f2_b, f_bf,
                                                       MR, 768, DFFD, 6);

    // fused residual + LN2 + max-pool + align + intent + window_num
    ln2_pool_intent_kernel<<<NWIN, 256, 0, stream>>>(x_bf, f_bf, ln2_g, ln2_bb, it_w, it_b,
                                                     seq_lens, out_pred, out_align, out_wn);
}

// Round 15
// 284.594 us; speedup vs baseline: 4.7669x; 1.1600x over previous
//
#include <hip/hip_runtime.h>
#include <hip/hip_bf16.h>

#define BB   16
#define SS   512
#define DD   768
#define NHH  4
#define HDD  192
#define DFFD 2048
#define NID  18
#define NW   510          // S - W + 1
#define NWIN (BB * NW)    // 8160 windows
#define MR   (NWIN * 3)   // 24480 encoder rows

typedef __attribute__((ext_vector_type(8))) short bf16x8;
typedef __attribute__((ext_vector_type(4))) short bf16x4;
typedef __attribute__((ext_vector_type(4))) float f32x4;
typedef __attribute__((ext_vector_type(2))) long long llx2;
typedef __hip_bfloat16 bf16;

__device__ __forceinline__ float b2f(bf16 x) { return __bfloat162float(x); }
__device__ __forceinline__ float s2f(short s) {
    return __bfloat162float(__builtin_bit_cast(bf16, (unsigned short)s));
}
__device__ __forceinline__ short f2s(float f) {
    return (short)__builtin_bit_cast(unsigned short, __float2bfloat16(f));
}

// Permuted fp8 layout within each 128B K-block: 8B unit (t = o>>5, kslot =
// (o>>3)&3) stored at 16B chunk c = kslot*2 + (t>>1), half h = t&1. A lane's
// b128 read of chunk kslot*2+s then yields fragments (t=2s, t=2s+1) directly,
// reproducing the verified conflict-free bf16 b128 pattern.
__device__ __forceinline__ int perm128(int o) {
    const int t  = o >> 5;
    const int ks = (o >> 3) & 3;
    return (ks * 2 + (t >> 1)) * 16 + (t & 1) * 8 + (o & 7);
}

// ---------------- fused f32 -> bf16/fp8(permuted) conversion ----------------
__device__ __forceinline__ void cvt_range(const float4* __restrict__ in,
                                          ushort4* __restrict__ out, int i)
{
    float4 f = in[i];
    ushort4 u;
    u.x = __builtin_bit_cast(unsigned short, __float2bfloat16(f.x));
    u.y = __builtin_bit_cast(unsigned short, __float2bfloat16(f.y));
    u.z = __builtin_bit_cast(unsigned short, __float2bfloat16(f.z));
    u.w = __builtin_bit_cast(unsigned short, __float2bfloat16(f.w));
    out[i] = u;
}
__device__ __forceinline__ void cvt_range_f8(const float4* __restrict__ in,
                                             unsigned char* __restrict__ out, int i)
{
    float4 f = in[i];
    int p = 0;
    p = __builtin_amdgcn_cvt_pk_fp8_f32(f.x, f.y, p, false);
    p = __builtin_amdgcn_cvt_pk_fp8_f32(f.z, f.w, p, true);
    const int ob = i * 4;
    const int o  = ob & 127;
    *(unsigned int*)(out + (ob - o) + perm128(o)) = (unsigned int)p;
}

#define CN0 1572864   // hidden (-> bf16 + fp8)
#define CN1 442368    // in_proj_w  (-> fp8)
#define CN2 147456    // out_proj_w (-> fp8)
#define CN3 393216    // ffn_w1     (-> fp8)
#define CN4 393216    // ffn_w2     (-> fp8)
#define CT  (CN0 + CN1 + CN2 + CN3 + CN4)

__global__ __launch_bounds__(256) void cvt_all_kernel(
    const float4* __restrict__ s0, ushort4* __restrict__ d0, unsigned char* __restrict__ d0f,
    const float4* __restrict__ s1, unsigned char* __restrict__ d1,
    const float4* __restrict__ s2, unsigned char* __restrict__ d2,
    const float4* __restrict__ s3, unsigned char* __restrict__ d3,
    const float4* __restrict__ s4, unsigned char* __restrict__ d4)
{
    for (int i = blockIdx.x * 256 + threadIdx.x; i < CT; i += gridDim.x * 256) {
        int j = i;
        if (j < CN0) { cvt_range(s0, d0, j); cvt_range_f8(s0, d0f, j); continue; }
        j -= CN0;
        if (j < CN1) { cvt_range_f8(s1, d1, j); continue; }
        j -= CN1;
        if (j < CN2) { cvt_range_f8(s2, d2, j); continue; }
        j -= CN2;
        if (j < CN3) { cvt_range_f8(s3, d3, j); continue; }
        j -= CN3;
        cvt_range_f8(s4, d4, j);
    }
}

// ---------------- 128x128 FP8 NT GEMM, BK=128, permuted layout, b128 reads ----
// A,B fp8 e4m3 [rows][K] in PERMUTED layout (perm128 within each 128B K-block).
// LDS [128 rows][128 B]/operand; staging + 16B-chunk XOR swizzle identical to
// the verified bf16 kernel. Lane reads 2x b128 per row -> 4 sub-tile frags.
// NOTE: no sched_barrier fences / same-buffer prefetch (round-12 spill lesson).
template<bool RELU, bool OUT8>
__global__ void gemm_f8(const unsigned char* __restrict__ A, const unsigned char* __restrict__ Bm,
                        const float* __restrict__ bias, void* __restrict__ Cv,
                        int M, int N, int K, int nx)
{
    __shared__ __align__(16) char smem[32768];
    char* smemc = smem;

    const int nwg  = gridDim.x;
    const int orig = blockIdx.x;
    const int xcd  = orig & 7;
    const int idx  = orig >> 3;
    const int q8   = nwg >> 3, r8 = nwg & 7;
    const int newid = (xcd < r8 ? xcd * (q8 + 1) : r8 * (q8 + 1) + (xcd - r8) * q8) + idx;
    const int row0 = (newid / nx) * 128;
    const int col0 = (newid % nx) * 128;

    const int tid = threadIdx.x;
    const int ln  = tid & 63;
    const int wv  = tid >> 6;
    const int wm = (wv >> 1) * 64;
    const int wn = (wv & 1) * 64;
    const int lrow  = ln & 15;
    const int kslot = ln >> 4;
    const int xk0 = ((kslot * 2)     ^ (lrow & 7)) << 4;   // frags t0,t1
    const int xk1 = ((kslot * 2 + 1) ^ (lrow & 7)) << 4;   // frags t2,t3

    // staging: identical byte pattern to verified bf16 kernel
    const int srow = ln >> 3;
    const int ce   = ((ln & 7) ^ srow) * 16;     // pre-swizzled source byte offset
    const int rb8  = wv * 32 + srow;
    const unsigned char* pA[4];
    const unsigned char* pB[4];
    #pragma unroll
    for (int i = 0; i < 4; ++i) {
        int ar = row0 + rb8 + i * 8;
        if (ar > M - 1) ar = M - 1;
        pA[i] = A  + (size_t)ar * K + ce;
        pB[i] = Bm + (size_t)(col0 + rb8 + i * 8) * K + ce;
    }

    f32x4 acc[4][4] = {};

    for (int k0 = 0; k0 < K; k0 += 128) {
        #pragma unroll
        for (int i = 0; i < 4; ++i) {
            __builtin_amdgcn_global_load_lds(
                (const __attribute__((address_space(1))) void*)(pA[i] + k0),
                (__attribute__((address_space(3))) void*)(smemc + wv * 4096 + i * 1024), 16, 0, 0);
            __builtin_amdgcn_global_load_lds(
                (const __attribute__((address_space(1))) void*)(pB[i] + k0),
                (__attribute__((address_space(3))) void*)(smemc + 16384 + wv * 4096 + i * 1024), 16, 0, 0);
        }
        __syncthreads();
        llx2 a0[4], a1[4], b0[4], b1[4];
        #pragma unroll
        for (int mi = 0; mi < 4; ++mi) {
            const int rb = (wm + mi * 16 + lrow) * 128;
            a0[mi] = *(const llx2*)(smemc + rb + xk0);
            a1[mi] = *(const llx2*)(smemc + rb + xk1);
        }
        #pragma unroll
        for (int ni = 0; ni < 4; ++ni) {
            const int rb = 16384 + (wn + ni * 16 + lrow) * 128;
            b0[ni] = *(const llx2*)(smemc + rb + xk0);
            b1[ni] = *(const llx2*)(smemc + rb + xk1);
        }
        #pragma unroll
        for (int mi = 0; mi < 4; ++mi)
            #pragma unroll
            for (int ni = 0; ni < 4; ++ni) {
                acc[mi][ni] = __builtin_amdgcn_mfma_f32_16x16x32_fp8_fp8(a0[mi][0], b0[ni][0], acc[mi][ni], 0, 0, 0);
                acc[mi][ni] = __builtin_amdgcn_mfma_f32_16x16x32_fp8_fp8(a0[mi][1], b0[ni][1], acc[mi][ni], 0, 0, 0);
                acc[mi][ni] = __builtin_amdgcn_mfma_f32_16x16x32_fp8_fp8(a1[mi][0], b1[ni][0], acc[mi][ni], 0, 0, 0);
                acc[mi][ni] = __builtin_amdgcn_mfma_f32_16x16x32_fp8_fp8(a1[mi][1], b1[ni][1], acc[mi][ni], 0, 0, 0);
            }
        __syncthreads();
    }

    #pragma unroll
    for (int mi = 0; mi < 4; ++mi) {
        #pragma unroll
        for (int ni = 0; ni < 4; ++ni) {
            const int col = col0 + wn + ni * 16 + lrow;
            const float bb = bias[col];
            #pragma unroll
            for (int r = 0; r < 4; ++r) {
                const int row = row0 + wm + mi * 16 + (ln >> 4) * 4 + r;
                if (row < M) {
                    float v = acc[mi][ni][r] + bb;
                    if (RELU) v = fmaxf(v, 0.0f);
                    if (OUT8) {
                        int p = __builtin_amdgcn_cvt_pk_fp8_f32(v, v, 0, false);
                        const int o = col & 127;
                        ((unsigned char*)Cv)[(size_t)row * N + (col - o) + perm128(o)] =
                            (unsigned char)(p & 0xff);
                    } else {
                        ((bf16*)Cv)[(size_t)row * N + col] = __float2bfloat16(v);
                    }
                }
            }
        }
    }
}

// ---------------- attention over W=3 per (window, head): one wave each ----------------
// Reads qkv bf16; writes attn output as PERMUTED fp8 (out_proj input).
__global__ __launch_bounds__(256) void attn_kernel(const bf16* __restrict__ qkv,
                                                   unsigned char* __restrict__ o8)
{
    const int m  = blockIdx.x;
    const int h  = threadIdx.x >> 6;
    const int ln = threadIdx.x & 63;
    const int bb = m / NW, n = m - bb * NW;
    const bool act = ln < 48;
    const size_t base = (size_t)(bb * SS + n) * (3 * DD) + h * HDD + 4 * ln;
    float q[3][4], k[3][4], v[3][4];
    #pragma unroll
    for (int j = 0; j < 3; ++j) {
        if (act) {
            const size_t idx = base + (size_t)j * (3 * DD);
            ushort4 q4 = *(const ushort4*)(qkv + idx);
            ushort4 k4 = *(const ushort4*)(qkv + idx + DD);
            ushort4 v4 = *(const ushort4*)(qkv + idx + 2 * DD);
            q[j][0] = s2f((short)q4.x); q[j][1] = s2f((short)q4.y);
            q[j][2] = s2f((short)q4.z); q[j][3] = s2f((short)q4.w);
            k[j][0] = s2f((short)k4.x); k[j][1] = s2f((short)k4.y);
            k[j][2] = s2f((short)k4.z); k[j][3] = s2f((short)k4.w);
            v[j][0] = s2f((short)v4.x); v[j][1] = s2f((short)v4.y);
            v[j][2] = s2f((short)v4.z); v[j][3] = s2f((short)v4.w);
        } else {
            #pragma unroll
            for (int c = 0; c < 4; ++c) { q[j][c] = 0.f; k[j][c] = 0.f; v[j][c] = 0.f; }
        }
    }
    float s[3][3];
    #pragma unroll
    for (int i = 0; i < 3; ++i)
        #pragma unroll
        for (int j = 0; j < 3; ++j)
            s[i][j] = q[i][0]*k[j][0] + q[i][1]*k[j][1] + q[i][2]*k[j][2] + q[i][3]*k[j][3];
    #pragma unroll
    for (int off = 32; off >= 1; off >>= 1)
        #pragma unroll
        for (int i = 0; i < 3; ++i)
            #pragma unroll
            for (int j = 0; j < 3; ++j)
                s[i][j] += __shfl_xor(s[i][j], off);
    const float scale = 0.07216878364870322f; // 1/sqrt(192)
    float p[3][3];
    #pragma unroll
    for (int i = 0; i < 3; ++i) {
        float mx = fmaxf(s[i][0], fmaxf(s[i][1], s[i][2])) * scale;
        float e0 = expf(s[i][0] * scale - mx);
        float e1 = expf(s[i][1] * scale - mx);
        float e2 = expf(s[i][2] * scale - mx);
        float inv = 1.0f / (e0 + e1 + e2);
        p[i][0] = e0 * inv; p[i][1] = e1 * inv; p[i][2] = e2 * inv;
    }
    if (act) {
        const int d = h * HDD + 4 * ln;
        const int o = d & 127;
        const int po = perm128(o);
        #pragma unroll
        for (int i = 0; i < 3; ++i) {
            float ov[4];
            #pragma unroll
            for (int c = 0; c < 4; ++c)
                ov[c] = p[i][0]*v[0][c] + p[i][1]*v[1][c] + p[i][2]*v[2][c];
            int pk = 0;
            pk = __builtin_amdgcn_cvt_pk_fp8_f32(ov[0], ov[1], pk, false);
            pk = __builtin_amdgcn_cvt_pk_fp8_f32(ov[2], ov[3], pk, true);
            *(unsigned int*)(o8 + (size_t)(m * 3 + i) * DD + (d - o) + po) = (unsigned int)pk;
        }
    }
}

// ---------------- residual + LN1: wave-per-row; emits bf16 x AND permuted fp8 x ----
__global__ __launch_bounds__(256) void ln1_kernel(const bf16* __restrict__ xa,
                                                  const bf16* __restrict__ xb,
                                                  const float* __restrict__ gamma,
                                                  const float* __restrict__ beta,
                                                  bf16* __restrict__ out,
                                                  unsigned char* __restrict__ out8)
{
    const int r  = blockIdx.x * 4 + (threadIdx.x >> 6);
    const int ln = threadIdx.x & 63;
    const size_t rb = (size_t)r * DD;
    const int m = r / 3, i = r - m * 3;
    const int bb = m / NW, n = m - bb * NW;
    const size_t ab = (size_t)(bb * SS + n + i) * DD;
    const int e0 = ln * 8, e1 = 512 + ln * 4;
    bf16x8 a0 = *(const bf16x8*)(xa + ab + e0);
    bf16x8 b0 = *(const bf16x8*)(xb + rb + e0);
    bf16x4 a1 = *(const bf16x4*)(xa + ab + e1);
    bf16x4 b1 = *(const bf16x4*)(xb + rb + e1);
    float v[12];
    #pragma unroll
    for (int c = 0; c < 8; ++c) v[c] = s2f(a0[c]) + s2f(b0[c]);
    #pragma unroll
    for (int c = 0; c < 4; ++c) v[8 + c] = s2f(a1[c]) + s2f(b1[c]);
    float s1 = 0.f, s2 = 0.f;
    #pragma unroll
    for (int c = 0; c < 12; ++c) { s1 += v[c]; s2 += v[c] * v[c]; }
    #pragma unroll
    for (int off = 32; off >= 1; off >>= 1) {
        s1 += __shfl_xor(s1, off);
        s2 += __shfl_xor(s2, off);
    }
    const float mean = s1 * (1.0f / 768.0f);
    const float var  = fmaxf(s2 * (1.0f / 768.0f) - mean * mean, 0.0f);
    const float inv  = rsqrtf(var + 1e-5f);
    float4 g0 = *(const float4*)(gamma + e0);
    float4 g1 = *(const float4*)(gamma + e0 + 4);
    float4 g2 = *(const float4*)(gamma + e1);
    float4 t0 = *(const float4*)(beta + e0);
    float4 t1 = *(const float4*)(beta + e0 + 4);
    float4 t2 = *(const float4*)(beta + e1);
    const float gg[12] = {g0.x,g0.y,g0.z,g0.w,g1.x,g1.y,g1.z,g1.w,g2.x,g2.y,g2.z,g2.w};
    const float tt[12] = {t0.x,t0.y,t0.z,t0.w,t1.x,t1.y,t1.z,t1.w,t2.x,t2.y,t2.z,t2.w};
    float o_[12];
    #pragma unroll
    for (int c = 0; c < 12; ++c) o_[c] = (v[c] - mean) * inv * gg[c] + tt[c];
    bf16x8 o0; bf16x4 o1;
    #pragma unroll
    for (int c = 0; c < 8; ++c) o0[c] = f2s(o_[c]);
    #pragma unroll
    for (int c = 0; c < 4; ++c) o1[c] = f2s(o_[8 + c]);
    *(bf16x8*)(out + rb + e0) = o0;
    *(bf16x4*)(out + rb + e1) = o1;
    int p0 = 0, p1 = 0, p2 = 0;
    p0 = __builtin_amdgcn_cvt_pk_fp8_f32(o_[0], o_[1], p0, false);
    p0 = __builtin_amdgcn_cvt_pk_fp8_f32(o_[2], o_[3], p0, true);
    p1 = __builtin_amdgcn_cvt_pk_fp8_f32(o_[4], o_[5], p1, false);
    p1 = __builtin_amdgcn_cvt_pk_fp8_f32(o_[6], o_[7], p1, true);
    p2 = __builtin_amdgcn_cvt_pk_fp8_f32(o_[8], o_[9], p2, false);
    p2 = __builtin_amdgcn_cvt_pk_fp8_f32(o_[10], o_[11], p2, true);
    {
        const int o = e0 & 127;
        const size_t pb = rb + (e0 - o);
        const int po = perm128(o);
        *(unsigned int*)(out8 + pb + po)     = (unsigned int)p0;
        *(unsigned int*)(out8 + pb + po + 4) = (unsigned int)p1;
    }
    {
        const int o = e1 & 127;
        const size_t pb = rb + (e1 - o);
        *(unsigned int*)(out8 + pb + perm128(o)) = (unsigned int)p2;
    }
}

// ---------------- fused residual + LN2 + max-pool + align + intent + window_num ----------------
__global__ __launch_bounds__(256) void ln2_pool_intent_kernel(
    const bf16* __restrict__ x, const bf16* __restrict__ f,
    const float* __restrict__ gamma, const float* __restrict__ beta,
    const float* __restrict__ iw, const float* __restrict__ ib,
    const int* __restrict__ seq,
    float* __restrict__ pred, float* __restrict__ align, float* __restrict__ wn_out)
{
    const int m  = blockIdx.x;
    const int bb = m / NW, n = m - bb * NW;
    const int wv = threadIdx.x >> 6, ln = threadIdx.x & 63;
    __shared__ float vsh[3][DD];
    __shared__ float pl[DD];
    if (wv < 3) {
        const size_t rb = (size_t)(m * 3 + wv) * DD;
        const int e0 = ln * 8, e1 = 512 + ln * 4;
        bf16x8 a0 = *(const bf16x8*)(x + rb + e0);
        bf16x8 b0 = *(const bf16x8*)(f + rb + e0);
        bf16x4 a1 = *(const bf16x4*)(x + rb + e1);
        bf16x4 b1 = *(const bf16x4*)(f + rb + e1);
        float v[12];
        #pragma unroll
        for (int c = 0; c < 8; ++c) v[c] = s2f(a0[c]) + s2f(b0[c]);
        #pragma unroll
        for (int c = 0; c < 4; ++c) v[8 + c] = s2f(a1[c]) + s2f(b1[c]);
        float s1 = 0.f, s2 = 0.f;
        #pragma unroll
        for (int c = 0; c < 12; ++c) { s1 += v[c]; s2 += v[c] * v[c]; }
        #pragma unroll
        for (int off = 32; off >= 1; off >>= 1) {
            s1 += __shfl_xor(s1, off);
            s2 += __shfl_xor(s2, off);
        }
        const float mean = s1 * (1.0f / 768.0f);
        const float var  = fmaxf(s2 * (1.0f / 768.0f) - mean * mean, 0.0f);
        const float inv  = rsqrtf(var + 1e-5f);
        float4 g0 = *(const float4*)(gamma + e0);
        float4 g1 = *(const float4*)(gamma + e0 + 4);
        float4 g2 = *(const float4*)(gamma + e1);
        float4 t0 = *(const float4*)(beta + e0);
        float4 t1 = *(const float4*)(beta + e0 + 4);
        float4 t2 = *(const float4*)(beta + e1);
        const float gg[12] = {g0.x,g0.y,g0.z,g0.w,g1.x,g1.y,g1.z,g1.w,g2.x,g2.y,g2.z,g2.w};
        const float tt[12] = {t0.x,t0.y,t0.z,t0.w,t1.x,t1.y,t1.z,t1.w,t2.x,t2.y,t2.z,t2.w};
        #pragma unroll
        for (int c = 0; c < 8; ++c) vsh[wv][e0 + c] = (v[c] - mean) * inv * gg[c] + tt[c];
        #pragma unroll
        for (int c = 0; c < 4; ++c) vsh[wv][e1 + c] = (v[8 + c] - mean) * inv * gg[8 + c] + tt[8 + c];
    }
    __syncthreads();
    const size_t ab = (size_t)bb * 512 * DD;
    #pragma unroll
    for (int t = 0; t < 3; ++t) {
        const int d = threadIdx.x + t * 256;
        float mx = fmaxf(vsh[0][d], fmaxf(vsh[1][d], vsh[2][d]));
        pl[d] = mx;
        align[ab + (size_t)(n + 1) * DD + d] = mx;
        if (n == 0)      align[ab + d] = mx;
        if (n == NW - 1) align[ab + (size_t)511 * DD + d] = mx;
    }
    if (m == 0 && threadIdx.x < BB) {
        int wn = seq[threadIdx.x] - 2;
        if (wn < 1) wn = 1;
        wn_out[threadIdx.x] = (float)wn;
    }
    __syncthreads();
    for (int c = wv; c < NID; c += 4) {
        float sum = 0.0f;
        #pragma unroll
        for (int t = 0; t < 12; ++t) {
            const int d = ln + t * 64;
            sum += pl[d] * iw[(size_t)c * DD + d];
        }
        #pragma unroll
        for (int off = 32; off >= 1; off >>= 1)
            sum += __shfl_xor(sum, off);
        if (ln == 0) pred[(size_t)m * NID + c] = sum + ib[c];
    }
}

extern "C" void kernel_launch(void* const* d_in, const int* in_sizes, int n_in,
                              void* d_out, int out_size, void* d_ws, size_t ws_size,
                              hipStream_t stream)
{
    const float* hidden   = (const float*)d_in[0];
    const int*   seq_lens = (const int*)d_in[1];
    const float* in_w     = (const float*)d_in[2];
    const float* in_b     = (const float*)d_in[3];
    const float* out_w    = (const float*)d_in[4];
    const float* out_b    = (const float*)d_in[5];
    const float* ln1_g    = (const float*)d_in[6];
    const float* ln1_bb   = (const float*)d_in[7];
    const float* ln2_g    = (const float*)d_in[8];
    const float* ln2_bb   = (const float*)d_in[9];
    const float* f1_w     = (const float*)d_in[10];
    const float* f1_b     = (const float*)d_in[11];
    const float* f2_w     = (const float*)d_in[12];
    const float* f2_b     = (const float*)d_in[13];
    const float* it_w     = (const float*)d_in[14];
    const float* it_b     = (const float*)d_in[15];

    // ---- workspace layout (187.5 MB total; ws >= 236.8 MB proven round 10) ----
    char* ws = (char*)d_ws;
    bf16*          hid_bf  = (bf16*)(ws + 0);                   // 12,582,912
    unsigned char* hid_f8  = (unsigned char*)(ws + 12582912);   //  6,291,456
    unsigned char* win_f8  = (unsigned char*)(ws + 18874368);   //  1,769,472
    unsigned char* wout_f8 = (unsigned char*)(ws + 20643840);   //    589,824
    unsigned char* wf1_f8  = (unsigned char*)(ws + 21233664);   //  1,572,864
    unsigned char* wf2_f8  = (unsigned char*)(ws + 22806528);   //  1,572,864
    bf16*          qkv_bf  = (bf16*)(ws + 24379392);            // R1: qkv -> oproj -> f (37,748,736)
    bf16*          oproj_bf= qkv_bf;
    bf16*          f_bf    = qkv_bf;
    unsigned char* o_f8    = (unsigned char*)(ws + 62128128);   // 18,800,640
    bf16*          x_bf    = (bf16*)(ws + 80928768);            // 37,601,280
    unsigned char* x_f8    = (unsigned char*)(ws + 118530048);  // 18,800,640
    unsigned char* h_f8    = (unsigned char*)(ws + 137330688);  // 50,135,040 -> ends 187,465,728

    float* out_pred  = (float*)d_out;           // 146880
    float* out_wn    = out_pred + 146880;       // 16
    float* out_align = out_pred + 146896;       // 6,291,456

    // fused conversions: hidden -> bf16 + permuted fp8; all 4 weights -> permuted fp8
    cvt_all_kernel<<<2048, 256, 0, stream>>>(
        (const float4*)hidden, (ushort4*)hid_bf, hid_f8,
        (const float4*)in_w,   win_f8,
        (const float4*)out_w,  wout_f8,
        (const float4*)f1_w,   wf1_f8,
        (const float4*)f2_w,   wf2_f8);

    // QKV: [8192,768] x [2304,768]^T -> bf16  (fp8 engine)
    gemm_f8<false, false><<<64 * 18, 256, 0, stream>>>(hid_f8, win_f8, in_b, qkv_bf,
                                                       8192, 2304, 768, 18);
    // attention per (window, head); emits permuted fp8 o
    attn_kernel<<<NWIN, 256, 0, stream>>>(qkv_bf, o_f8);
    // out_proj: [24480,768] x [768,768]^T -> bf16 (into R1, qkv dead)
    gemm_f8<false, false><<<192 * 6, 256, 0, stream>>>(o_f8, wout_f8, out_b, oproj_bf,
                                                       MR, 768, 768, 6);
    // x = LN1(win + oproj): bf16 x (residual/tail) + permuted fp8 x (FFN1 input)
    ln1_kernel<<<MR / 4, 256, 0, stream>>>(hid_bf, oproj_bf, ln1_g, ln1_bb, x_bf, x_f8);

    // FFN1: [24480,768] x [2048,768]^T + ReLU -> permuted fp8 h
    gemm_f8<true, true><<<192 * 16, 256, 0, stream>>>(x_f8, wf1_f8, f1_b, h_f8,
                                                      MR, DFFD, 768, 16);
    // FFN2: [24480,2048] x [768,2048]^T -> bf16 f (into R1, oproj dead)
    gemm_f8<false, false><<<192 * 6, 256, 0, stream>>>(h_f8, wf2_f8, f2_b, f_bf,
                                                       MR, 768, DFFD, 6);

    // fused residual + LN2 + max-pool + align + intent + window_num
    ln2_pool_intent_kernel<<<NWIN, 256, 0, stream>>>(x_bf, f_bf, ln2_g, ln2_bb, it_w, it_b,
                                                     seq_lens, out_pred, out_align, out_wn);
}